// Round 3
// baseline (4134.201 us; speedup 1.0000x reference)
//
#include <hip/hip_runtime.h>
#include <hip/hip_bf16.h>
#include <math.h>

#define B_  2
#define L_  1024
#define DM  1024
#define DI  2048
#define DS  16
#define DC  4
#define RK  64
#define GG  96      // RK + 2*DS
#define LN_EPS 1e-5f

using bf16 = __hip_bfloat16;

__device__ __forceinline__ float ldf(const float* p){ return *p; }
__device__ __forceinline__ float ldf(const bf16*  p){ return __bfloat162float(*p); }

// C[M x N] = A[M x K] (row stride lda) * W[N x K]^T (row stride ldw)
// EPI: 0 = store, 1 = bias + softplus, 2 = read-add-store
template<typename TA, typename TW, int EPI>
__global__ __launch_bounds__(256)
void gemm_bt(const TA* __restrict__ A, int lda,
             const TW* __restrict__ W, int ldw,
             float* __restrict__ C, int ldc,
             int M, int N, int K, int flipA, int flipC,
             const TW* __restrict__ bias)
{
    __shared__ float As[16][65];
    __shared__ float Ws[16][65];
    const int m0 = blockIdx.y * 64;
    const int n0 = blockIdx.x * 64;
    const int tx = threadIdx.x, ty = threadIdx.y;
    const int tid = ty * 16 + tx;
    float acc[4][4] = {};

    for (int k0 = 0; k0 < K; k0 += 16) {
        for (int e = tid; e < 1024; e += 256) {
            int mm = e >> 4, kk = e & 15;
            int gm = m0 + mm, gk = k0 + kk;
            float va = 0.f;
            if (gm < M && gk < K) {
                int pr = gm;
                if (flipA) { int b = gm / L_; int l = gm % L_; pr = b * L_ + (L_ - 1 - l); }
                va = ldf(&A[(size_t)pr * lda + gk]);
            }
            As[kk][mm] = va;
            int gn = n0 + mm;
            float vw = 0.f;
            if (gn < N && gk < K) vw = ldf(&W[(size_t)gn * ldw + gk]);
            Ws[kk][mm] = vw;
        }
        __syncthreads();
        #pragma unroll
        for (int k = 0; k < 16; k++) {
            float a[4], w[4];
            #pragma unroll
            for (int i = 0; i < 4; i++) a[i] = As[k][ty * 4 + i];
            #pragma unroll
            for (int j = 0; j < 4; j++) w[j] = Ws[k][tx * 4 + j];
            #pragma unroll
            for (int i = 0; i < 4; i++)
                #pragma unroll
                for (int j = 0; j < 4; j++) acc[i][j] += a[i] * w[j];
        }
        __syncthreads();
    }

    #pragma unroll
    for (int i = 0; i < 4; i++) {
        int m = m0 + ty * 4 + i;
        if (m >= M) continue;
        int mo = m;
        if (flipC) { int b = m / L_; int l = m % L_; mo = b * L_ + (L_ - 1 - l); }
        #pragma unroll
        for (int j = 0; j < 4; j++) {
            int n = n0 + tx * 4 + j;
            if (n >= N) continue;
            float v = acc[i][j];
            if (EPI == 1) { v += ldf(&bias[n]); v = (v > 20.f) ? v : log1pf(expf(v)); }
            float* p = &C[(size_t)mo * ldc + n];
            if (EPI == 2) v += *p;
            *p = v;
        }
    }
}

// xc[b,l,d] = silu(conv_b[d] + sum_k xi[b, l+k-3, d] * conv_w[d,k]),  xi = xz[..., 0:DI]
__global__ __launch_bounds__(256)
void conv_silu_kernel(const float* __restrict__ xz, const float* __restrict__ conv_w,
                      const float* __restrict__ conv_b, float* __restrict__ xc)
{
    int idx = blockIdx.x * 256 + threadIdx.x;           // over B*L*DI
    int d = idx % DI; int bl = idx / DI; int l = bl % L_; int b = bl / L_;
    float acc = ldf(&conv_b[d]);
    #pragma unroll
    for (int k = 0; k < DC; k++) {
        int ls = l + k - (DC - 1);
        if (ls >= 0)
            acc += xz[(size_t)(b * L_ + ls) * (2 * DI) + d] * ldf(&conv_w[d * DC + k]);
    }
    xc[idx] = acc / (1.f + expf(-acc));
}

// One wave = 4 channels x 16 states. Sequential over L. Writes gated y into the dt buffer.
__global__ __launch_bounds__(256)
void scan_kernel(const float* __restrict__ dbl, const float* __restrict__ xc,
                 float* __restrict__ dtys, const float* __restrict__ xz,
                 const float* __restrict__ A_log, const float* __restrict__ Dp)
{
    int t = blockIdx.x * 256 + threadIdx.x;
    int lane = t & 63; int w = t >> 6;                 // wave id 0..1023
    int n = lane & 15; int dsub = lane >> 4;           // 0..3
    int b = w / (DI / 4); int dgrp = w % (DI / 4);
    int d = dgrp * 4 + dsub;

    float Aval = -expf(ldf(&A_log[d * DS + n]));
    float Dval = ldf(&Dp[d]);
    float h = 0.f;
    const float* dblb = dbl + (size_t)(b * L_) * GG;

    for (int l = 0; l < L_; l++) {
        size_t ro = (size_t)(b * L_ + l);
        float dt = dtys[ro * DI + d];
        float x  = xc[ro * DI + d];
        float Bn = dblb[l * GG + RK + n];
        float Cn = dblb[l * GG + RK + DS + n];
        float dA = expf(dt * Aval);
        h = dA * h + dt * x * Bn;
        float c = h * Cn;
        c += __shfl_xor(c, 8, 16);
        c += __shfl_xor(c, 4, 16);
        c += __shfl_xor(c, 2, 16);
        c += __shfl_xor(c, 1, 16);
        if (n == 0) {
            float z = xz[ro * (2 * DI) + DI + d];
            float y = (c + x * Dval) * (z / (1.f + expf(-z)));
            dtys[ro * DI + d] = y;
        }
    }
}

__global__ __launch_bounds__(256)
void ln_kernel(const float* __restrict__ yo, const float* __restrict__ gamma,
               const float* __restrict__ beta, float* __restrict__ out)
{
    int row = blockIdx.x;                               // 0..B*L-1
    const float* r = yo + (size_t)row * DM;
    float s = 0.f, s2 = 0.f;
    for (int i = threadIdx.x; i < DM; i += 256) { float v = r[i]; s += v; s2 += v * v; }
    #pragma unroll
    for (int o = 32; o > 0; o >>= 1) { s += __shfl_down(s, o); s2 += __shfl_down(s2, o); }
    __shared__ float sw[4], sw2[4];
    int wid = threadIdx.x >> 6, ln = threadIdx.x & 63;
    if (ln == 0) { sw[wid] = s; sw2[wid] = s2; }
    __syncthreads();
    if (threadIdx.x == 0) {
        float a = 0.f, b2 = 0.f;
        for (int i = 0; i < 4; i++) { a += sw[i]; b2 += sw2[i]; }
        sw[0] = a; sw2[0] = b2;
    }
    __syncthreads();
    float mean = sw[0] / DM;
    float var  = sw2[0] / DM - mean * mean;
    float rstd = rsqrtf(var + LN_EPS);
    for (int i = threadIdx.x; i < DM; i += 256) {
        float v = (r[i] - mean) * rstd;
        out[(size_t)row * DM + i] = ldf(&gamma[i]) * v + ldf(&beta[i]);
    }
}

extern "C" void kernel_launch(void* const* d_in, const int* in_sizes, int n_in,
                              void* d_out, int out_size, void* d_ws, size_t ws_size,
                              hipStream_t stream)
{
    const float* x = (const float*)d_in[0];

    float* ws  = (float*)d_ws;
    float* xz  = ws;                                  // B*L*2*DI = 8,388,608
    float* xc  = xz  + (size_t)B_ * L_ * 2 * DI;      // B*L*DI   = 4,194,304
    float* dbl = xc  + (size_t)B_ * L_ * DI;          // B*L*GG   =   196,608
    float* dt  = dbl + (size_t)B_ * L_ * GG;          // B*L*DI   = 4,194,304 (becomes ys)
    float* yo  = dt  + (size_t)B_ * L_ * DI;          // B*L*DM   = 2,097,152
    // total ~76.3 MB of fp32 scratch

    dim3 blk(16, 16);
    const int M = B_ * L_;

    for (int dir = 0; dir < 2; dir++) {
        const float* in_proj   = (const float*)d_in[1 + dir * 9 + 0];
        const float* conv_w    = (const float*)d_in[1 + dir * 9 + 1];
        const float* conv_b    = (const float*)d_in[1 + dir * 9 + 2];
        const float* x_proj    = (const float*)d_in[1 + dir * 9 + 3];
        const float* dt_proj_w = (const float*)d_in[1 + dir * 9 + 4];
        const float* dt_proj_b = (const float*)d_in[1 + dir * 9 + 5];
        const float* A_log     = (const float*)d_in[1 + dir * 9 + 6];
        const float* Dp        = (const float*)d_in[1 + dir * 9 + 7];
        const float* out_proj  = (const float*)d_in[1 + dir * 9 + 8];

        // GEMM1: xz = x(flip?) @ in_proj^T            M x 4096, K=1024
        dim3 g1((2 * DI) / 64, M / 64);
        gemm_bt<float, float, 0><<<g1, blk, 0, stream>>>(
            x, DM, in_proj, DM, xz, 2 * DI, M, 2 * DI, DM, dir, 0, nullptr);

        // conv + silu
        conv_silu_kernel<<<(B_ * L_ * DI) / 256, 256, 0, stream>>>(xz, conv_w, conv_b, xc);

        // GEMM2: dbl = xc @ x_proj^T                  M x 96, K=2048
        dim3 g2((GG + 63) / 64, M / 64);
        gemm_bt<float, float, 0><<<g2, blk, 0, stream>>>(
            xc, DI, x_proj, DI, dbl, GG, M, GG, DI, 0, 0, nullptr);

        // GEMM3: dt = softplus(dbl[:, :64] @ dt_proj_w^T + b)   M x 2048, K=64
        dim3 g3(DI / 64, M / 64);
        gemm_bt<float, float, 1><<<g3, blk, 0, stream>>>(
            dbl, GG, dt_proj_w, RK, dt, DI, M, DI, RK, 0, 0, dt_proj_b);

        // selective scan + D-skip + z-gating (ys written into dt buffer)
        scan_kernel<<<256, 256, 0, stream>>>(dbl, xc, dt, xz, A_log, Dp);

        // GEMM4: yo (+)= ys @ out_proj^T              M x 1024, K=2048
        dim3 g4(DM / 64, M / 64);
        if (dir == 0)
            gemm_bt<float, float, 0><<<g4, blk, 0, stream>>>(
                dt, DI, out_proj, DI, yo, DM, M, DM, DI, 0, 0, nullptr);
        else
            gemm_bt<float, float, 2><<<g4, blk, 0, stream>>>(
                dt, DI, out_proj, DI, yo, DM, M, DM, DI, 0, 1, nullptr);
    }

    ln_kernel<<<B_ * L_, 256, 0, stream>>>(
        yo, (const float*)d_in[19], (const float*)d_in[20], (float*)d_out);
}

// Round 4
// 2814.301 us; speedup vs baseline: 1.4690x; 1.4690x over previous
//
#include <hip/hip_runtime.h>
#include <hip/hip_bf16.h>
#include <math.h>

#define B_  2
#define L_  1024
#define DM  1024
#define DI  2048
#define DS  16
#define DC  4
#define RK  64
#define GG  96      // RK + 2*DS
#define NC  32      // scan chunks
#define CL  32      // L_/NC
#define LN_EPS 1e-5f

using bf16 = __hip_bfloat16;

__device__ __forceinline__ float ldf(const float* p){ return *p; }
__device__ __forceinline__ float ldf(const bf16*  p){ return __bfloat162float(*p); }

// C[M x N] = A[M x K] (row stride lda) * W[N x K]^T (row stride ldw)
// EPI: 0 = store, 1 = bias + softplus, 2 = read-add-store
template<typename TA, typename TW, int EPI>
__global__ __launch_bounds__(256)
void gemm_bt(const TA* __restrict__ A, int lda,
             const TW* __restrict__ W, int ldw,
             float* __restrict__ C, int ldc,
             int M, int N, int K, int flipA, int flipC,
             const TW* __restrict__ bias)
{
    __shared__ float As[16][65];
    __shared__ float Ws[16][65];
    const int m0 = blockIdx.y * 64;
    const int n0 = blockIdx.x * 64;
    const int tx = threadIdx.x, ty = threadIdx.y;
    const int tid = ty * 16 + tx;
    float acc[4][4] = {};

    for (int k0 = 0; k0 < K; k0 += 16) {
        for (int e = tid; e < 1024; e += 256) {
            int mm = e >> 4, kk = e & 15;
            int gm = m0 + mm, gk = k0 + kk;
            float va = 0.f;
            if (gm < M && gk < K) {
                int pr = gm;
                if (flipA) { int b = gm / L_; int l = gm % L_; pr = b * L_ + (L_ - 1 - l); }
                va = ldf(&A[(size_t)pr * lda + gk]);
            }
            As[kk][mm] = va;
            int gn = n0 + mm;
            float vw = 0.f;
            if (gn < N && gk < K) vw = ldf(&W[(size_t)gn * ldw + gk]);
            Ws[kk][mm] = vw;
        }
        __syncthreads();
        #pragma unroll
        for (int k = 0; k < 16; k++) {
            float a[4], w[4];
            #pragma unroll
            for (int i = 0; i < 4; i++) a[i] = As[k][ty * 4 + i];
            #pragma unroll
            for (int j = 0; j < 4; j++) w[j] = Ws[k][tx * 4 + j];
            #pragma unroll
            for (int i = 0; i < 4; i++)
                #pragma unroll
                for (int j = 0; j < 4; j++) acc[i][j] += a[i] * w[j];
        }
        __syncthreads();
    }

    #pragma unroll
    for (int i = 0; i < 4; i++) {
        int m = m0 + ty * 4 + i;
        if (m >= M) continue;
        int mo = m;
        if (flipC) { int b = m / L_; int l = m % L_; mo = b * L_ + (L_ - 1 - l); }
        #pragma unroll
        for (int j = 0; j < 4; j++) {
            int n = n0 + tx * 4 + j;
            if (n >= N) continue;
            float v = acc[i][j];
            if (EPI == 1) { v += ldf(&bias[n]); v = (v > 20.f) ? v : log1pf(expf(v)); }
            float* p = &C[(size_t)mo * ldc + n];
            if (EPI == 2) v += *p;
            *p = v;
        }
    }
}

// xc[b,l,d] = silu(conv_b[d] + sum_k xi[b, l+k-3, d] * conv_w[d,k]),  xi = xz[..., 0:DI]
__global__ __launch_bounds__(256)
void conv_silu_kernel(const float* __restrict__ xz, const float* __restrict__ conv_w,
                      const float* __restrict__ conv_b, float* __restrict__ xc)
{
    int idx = blockIdx.x * 256 + threadIdx.x;           // over B*L*DI
    int d = idx % DI; int bl = idx / DI; int l = bl % L_; int b = bl / L_;
    float acc = ldf(&conv_b[d]);
    #pragma unroll
    for (int k = 0; k < DC; k++) {
        int ls = l + k - (DC - 1);
        if (ls >= 0)
            acc += xz[(size_t)(b * L_ + ls) * (2 * DI) + d] * ldf(&conv_w[d * DC + k]);
    }
    xc[idx] = acc / (1.f + expf(-acc));
}

// ---------------- chunk-parallel selective scan ----------------
// Phase A: thread per (b,d,chunk,n): local scan over CL steps, h0=0.
// t layout: (((b*DI + d)*NC + c)*DS + n)
__global__ __launch_bounds__(256)
void scan_phaseA(const float* __restrict__ dbl, const float* __restrict__ xc,
                 const float* __restrict__ dts, const float* __restrict__ A_log,
                 float* __restrict__ Pbuf, float* __restrict__ Hbuf)
{
    int t = blockIdx.x * 256 + threadIdx.x;
    int n = t & 15;
    int c = (t >> 4) & (NC - 1);
    int d = (t >> 9) & (DI - 1);
    int b = t >> 20;
    float Aval = -expf(A_log[d * DS + n]);
    float P = 1.f, H = 0.f;
    int l0 = c * CL;
    for (int i = 0; i < CL; i++) {
        size_t ro = (size_t)(b * L_ + l0 + i);
        float dt = dts[ro * DI + d];
        float x  = xc[ro * DI + d];
        float Bn = dbl[ro * GG + RK + n];
        float dA = expf(dt * Aval);
        P *= dA;
        H = dA * H + dt * x * Bn;
    }
    Pbuf[t] = P;
    Hbuf[t] = H;
}

// Phase B: thread per (b,d,n): sequential combine over NC chunks.
// Converts Hbuf from local-end-state into chunk-entry-state (in place).
__global__ __launch_bounds__(256)
void scan_phaseB(const float* __restrict__ Pbuf, float* __restrict__ Hbuf)
{
    int t = blockIdx.x * 256 + threadIdx.x;   // (b*DI+d)*DS + n
    int n = t & 15; int bd = t >> 4;
    size_t base = (size_t)bd * NC * DS + n;
    float run = 0.f;
    for (int c = 0; c < NC; c++) {
        size_t idx = base + (size_t)c * DS;
        float P  = Pbuf[idx];
        float Hl = Hbuf[idx];
        Hbuf[idx] = run;                       // entry state for chunk c
        run = Hl + P * run;
    }
}

// Phase C: wave per (b, d-group-of-4, chunk); lanes = 16 n x 4 d.
// Re-runs the scan from the chunk-entry state, fused with C-contraction,
// D-skip and z-gating. Writes gated y into the dt buffer.
__global__ __launch_bounds__(256)
void scan_phaseC(const float* __restrict__ dbl, const float* __restrict__ xc,
                 float* __restrict__ dtys, const float* __restrict__ xz,
                 const float* __restrict__ A_log, const float* __restrict__ Dp,
                 const float* __restrict__ Hbuf)
{
    int t = blockIdx.x * 256 + threadIdx.x;
    int lane = t & 63; int w = t >> 6;
    int n = lane & 15, dsub = lane >> 4;
    int c = w & (NC - 1);
    int dgrp = (w >> 5) & 511;
    int b = w >> 14;
    int d = dgrp * 4 + dsub;

    float Aval = -expf(A_log[d * DS + n]);
    float Dval = Dp[d];
    float h = Hbuf[((size_t)(b * DI + d) * NC + c) * DS + n];
    int l0 = c * CL;

    for (int i = 0; i < CL; i++) {
        size_t ro = (size_t)(b * L_ + l0 + i);
        float dt = dtys[ro * DI + d];
        float x  = xc[ro * DI + d];
        float Bn = dbl[ro * GG + RK + n];
        float Cn = dbl[ro * GG + RK + DS + n];
        float dA = expf(dt * Aval);
        h = dA * h + dt * x * Bn;
        float cc = h * Cn;
        cc += __shfl_xor(cc, 8, 16);
        cc += __shfl_xor(cc, 4, 16);
        cc += __shfl_xor(cc, 2, 16);
        cc += __shfl_xor(cc, 1, 16);
        if (n == 0) {
            float z = xz[ro * (2 * DI) + DI + d];
            dtys[ro * DI + d] = (cc + x * Dval) * (z / (1.f + expf(-z)));
        }
    }
}

// Fallback single-pass scan (used only if ws_size can't fit P/H scratch).
__global__ __launch_bounds__(256)
void scan_kernel(const float* __restrict__ dbl, const float* __restrict__ xc,
                 float* __restrict__ dtys, const float* __restrict__ xz,
                 const float* __restrict__ A_log, const float* __restrict__ Dp)
{
    int t = blockIdx.x * 256 + threadIdx.x;
    int lane = t & 63; int w = t >> 6;
    int n = lane & 15; int dsub = lane >> 4;
    int b = w / (DI / 4); int dgrp = w % (DI / 4);
    int d = dgrp * 4 + dsub;

    float Aval = -expf(A_log[d * DS + n]);
    float Dval = Dp[d];
    float h = 0.f;
    const float* dblb = dbl + (size_t)(b * L_) * GG;

    for (int l = 0; l < L_; l++) {
        size_t ro = (size_t)(b * L_ + l);
        float dt = dtys[ro * DI + d];
        float x  = xc[ro * DI + d];
        float Bn = dblb[l * GG + RK + n];
        float Cn = dblb[l * GG + RK + DS + n];
        float dA = expf(dt * Aval);
        h = dA * h + dt * x * Bn;
        float c = h * Cn;
        c += __shfl_xor(c, 8, 16);
        c += __shfl_xor(c, 4, 16);
        c += __shfl_xor(c, 2, 16);
        c += __shfl_xor(c, 1, 16);
        if (n == 0) {
            float z = xz[ro * (2 * DI) + DI + d];
            float y = (c + x * Dval) * (z / (1.f + expf(-z)));
            dtys[ro * DI + d] = y;
        }
    }
}

__global__ __launch_bounds__(256)
void ln_kernel(const float* __restrict__ yo, const float* __restrict__ gamma,
               const float* __restrict__ beta, float* __restrict__ out)
{
    int row = blockIdx.x;                               // 0..B*L-1
    const float* r = yo + (size_t)row * DM;
    float s = 0.f, s2 = 0.f;
    for (int i = threadIdx.x; i < DM; i += 256) { float v = r[i]; s += v; s2 += v * v; }
    #pragma unroll
    for (int o = 32; o > 0; o >>= 1) { s += __shfl_down(s, o); s2 += __shfl_down(s2, o); }
    __shared__ float sw[4], sw2[4];
    int wid = threadIdx.x >> 6, ln = threadIdx.x & 63;
    if (ln == 0) { sw[wid] = s; sw2[wid] = s2; }
    __syncthreads();
    if (threadIdx.x == 0) {
        float a = 0.f, b2 = 0.f;
        for (int i = 0; i < 4; i++) { a += sw[i]; b2 += sw2[i]; }
        sw[0] = a; sw2[0] = b2;
    }
    __syncthreads();
    float mean = sw[0] / DM;
    float var  = sw2[0] / DM - mean * mean;
    float rstd = rsqrtf(var + LN_EPS);
    for (int i = threadIdx.x; i < DM; i += 256) {
        float v = (r[i] - mean) * rstd;
        out[(size_t)row * DM + i] = ldf(&gamma[i]) * v + ldf(&beta[i]);
    }
}

extern "C" void kernel_launch(void* const* d_in, const int* in_sizes, int n_in,
                              void* d_out, int out_size, void* d_ws, size_t ws_size,
                              hipStream_t stream)
{
    const float* x = (const float*)d_in[0];

    float* ws  = (float*)d_ws;
    float* xz  = ws;                                  // B*L*2*DI = 8,388,608 f
    float* xc  = xz  + (size_t)B_ * L_ * 2 * DI;      // B*L*DI   = 4,194,304 f
    float* dbl = xc  + (size_t)B_ * L_ * DI;          // B*L*GG   =   196,608 f
    float* dt  = dbl + (size_t)B_ * L_ * GG;          // B*L*DI   = 4,194,304 f (becomes ys)
    float* yo  = dt  + (size_t)B_ * L_ * DI;          // B*L*DM   = 2,097,152 f
    float* Pb  = yo  + (size_t)B_ * L_ * DM;          // B*DI*NC*DS = 2,097,152 f
    float* Hb  = Pb  + (size_t)B_ * DI * NC * DS;     // B*DI*NC*DS = 2,097,152 f
    const size_t need_bytes = ((size_t)(Hb - ws) + (size_t)B_ * DI * NC * DS) * 4;
    const int use_chunked = (ws_size >= need_bytes);

    dim3 blk(16, 16);
    const int M = B_ * L_;

    for (int dir = 0; dir < 2; dir++) {
        const float* in_proj   = (const float*)d_in[1 + dir * 9 + 0];
        const float* conv_w    = (const float*)d_in[1 + dir * 9 + 1];
        const float* conv_b    = (const float*)d_in[1 + dir * 9 + 2];
        const float* x_proj    = (const float*)d_in[1 + dir * 9 + 3];
        const float* dt_proj_w = (const float*)d_in[1 + dir * 9 + 4];
        const float* dt_proj_b = (const float*)d_in[1 + dir * 9 + 5];
        const float* A_log     = (const float*)d_in[1 + dir * 9 + 6];
        const float* Dp        = (const float*)d_in[1 + dir * 9 + 7];
        const float* out_proj  = (const float*)d_in[1 + dir * 9 + 8];

        // GEMM1: xz = x(flip?) @ in_proj^T            M x 4096, K=1024
        dim3 g1((2 * DI) / 64, M / 64);
        gemm_bt<float, float, 0><<<g1, blk, 0, stream>>>(
            x, DM, in_proj, DM, xz, 2 * DI, M, 2 * DI, DM, dir, 0, nullptr);

        // conv + silu
        conv_silu_kernel<<<(B_ * L_ * DI) / 256, 256, 0, stream>>>(xz, conv_w, conv_b, xc);

        // GEMM2: dbl = xc @ x_proj^T                  M x 96, K=2048
        dim3 g2((GG + 63) / 64, M / 64);
        gemm_bt<float, float, 0><<<g2, blk, 0, stream>>>(
            xc, DI, x_proj, DI, dbl, GG, M, GG, DI, 0, 0, nullptr);

        // GEMM3: dt = softplus(dbl[:, :64] @ dt_proj_w^T + b)   M x 2048, K=64
        dim3 g3(DI / 64, M / 64);
        gemm_bt<float, float, 1><<<g3, blk, 0, stream>>>(
            dbl, GG, dt_proj_w, RK, dt, DI, M, DI, RK, 0, 0, dt_proj_b);

        // selective scan + D-skip + z-gating (ys written into dt buffer)
        if (use_chunked) {
            scan_phaseA<<<(B_ * DI * NC * DS) / 256, 256, 0, stream>>>(
                dbl, xc, dt, A_log, Pb, Hb);
            scan_phaseB<<<(B_ * DI * DS) / 256, 256, 0, stream>>>(Pb, Hb);
            scan_phaseC<<<(B_ * (DI / 4) * NC * 64) / 256, 256, 0, stream>>>(
                dbl, xc, dt, xz, A_log, Dp, Hb);
        } else {
            scan_kernel<<<256, 256, 0, stream>>>(dbl, xc, dt, xz, A_log, Dp);
        }

        // GEMM4: yo (+)= ys @ out_proj^T              M x 1024, K=2048
        dim3 g4(DM / 64, M / 64);
        if (dir == 0)
            gemm_bt<float, float, 0><<<g4, blk, 0, stream>>>(
                dt, DI, out_proj, DI, yo, DM, M, DM, DI, 0, 0, nullptr);
        else
            gemm_bt<float, float, 2><<<g4, blk, 0, stream>>>(
                dt, DI, out_proj, DI, yo, DM, M, DM, DI, 0, 1, nullptr);
    }

    ln_kernel<<<B_ * L_, 256, 0, stream>>>(
        yo, (const float*)d_in[19], (const float*)d_in[20], (float*)d_out);
}

// Round 5
// 1456.537 us; speedup vs baseline: 2.8384x; 1.9322x over previous
//
#include <hip/hip_runtime.h>
#include <hip/hip_bf16.h>
#include <math.h>

#define B_  2
#define L_  1024
#define DM  1024
#define DI  2048
#define DS  16
#define DC  4
#define RK  64
#define GG  96      // RK + 2*DS
#define NC  32      // scan chunks
#define CL  32      // L_/NC
#define LN_EPS 1e-5f

using bf16 = __hip_bfloat16;
typedef __attribute__((ext_vector_type(8))) short short8;
typedef __attribute__((ext_vector_type(4))) float f32x4;

__device__ __forceinline__ float ldf(const float* p){ return *p; }

__device__ __forceinline__ unsigned short f2bf(float f) {
    union { float f; unsigned u; } x; x.f = f;
    unsigned r = x.u + 0x7fffu + ((x.u >> 16) & 1u);   // round-to-nearest-even
    return (unsigned short)(r >> 16);
}

// ---------------- fp32 fallback / small GEMM ----------------
// C[M x N] = A[M x K] * W[N x K]^T ; EPI: 0 store, 1 bias+softplus, 2 read-add
template<int EPI>
__global__ __launch_bounds__(256)
void gemm_bt(const float* __restrict__ A, int lda,
             const float* __restrict__ W, int ldw,
             float* __restrict__ C, int ldc,
             int M, int N, int K, int flipA, int flipC,
             const float* __restrict__ bias)
{
    __shared__ float As[16][65];
    __shared__ float Ws[16][65];
    const int m0 = blockIdx.y * 64;
    const int n0 = blockIdx.x * 64;
    const int tx = threadIdx.x, ty = threadIdx.y;
    const int tid = ty * 16 + tx;
    float acc[4][4] = {};

    for (int k0 = 0; k0 < K; k0 += 16) {
        for (int e = tid; e < 1024; e += 256) {
            int mm = e >> 4, kk = e & 15;
            int gm = m0 + mm, gk = k0 + kk;
            float va = 0.f;
            if (gm < M && gk < K) {
                int pr = gm;
                if (flipA) { int b = gm / L_; int l = gm % L_; pr = b * L_ + (L_ - 1 - l); }
                va = A[(size_t)pr * lda + gk];
            }
            As[kk][mm] = va;
            int gn = n0 + mm;
            float vw = 0.f;
            if (gn < N && gk < K) vw = W[(size_t)gn * ldw + gk];
            Ws[kk][mm] = vw;
        }
        __syncthreads();
        #pragma unroll
        for (int k = 0; k < 16; k++) {
            float a[4], w[4];
            #pragma unroll
            for (int i = 0; i < 4; i++) a[i] = As[k][ty * 4 + i];
            #pragma unroll
            for (int j = 0; j < 4; j++) w[j] = Ws[k][tx * 4 + j];
            #pragma unroll
            for (int i = 0; i < 4; i++)
                #pragma unroll
                for (int j = 0; j < 4; j++) acc[i][j] += a[i] * w[j];
        }
        __syncthreads();
    }

    #pragma unroll
    for (int i = 0; i < 4; i++) {
        int m = m0 + ty * 4 + i;
        if (m >= M) continue;
        int mo = m;
        if (flipC) { int b = m / L_; int l = m % L_; mo = b * L_ + (L_ - 1 - l); }
        #pragma unroll
        for (int j = 0; j < 4; j++) {
            int n = n0 + tx * 4 + j;
            if (n >= N) continue;
            float v = acc[i][j];
            if (EPI == 1) { v += bias[n]; v = (v > 20.f) ? v : log1pf(expf(v)); }
            float* p = &C[(size_t)mo * ldc + n];
            if (EPI == 2) v += *p;
            *p = v;
        }
    }
}

// ---------------- bf16 MFMA GEMM (m97 structure) ----------------
// C[M x N] = A[M x K](bf16, row-major) * W[N x K]^T(bf16, row-major), fp32 out.
// Block 256 thr = 4 waves in 2x2; tile BM x BN; K-step 32.
template<int BM, int BN, int EPI>
__global__ __launch_bounds__(256)
void gemm_mfma(const bf16* __restrict__ A, const bf16* __restrict__ W,
               float* __restrict__ C, int ldc, int K, int flipC)
{
    constexpr int WMx = BM / 2, WNx = BN / 2, MT = WMx / 16, NT = WNx / 16;
    __shared__ __align__(16) bf16 As[BM * 32];
    __shared__ __align__(16) bf16 Bs[BN * 32];
    const int tid  = threadIdx.x;
    const int lane = tid & 63;
    const int wave = tid >> 6;
    const int wm = wave >> 1, wn = wave & 1;
    const int r16 = lane & 15, quad = lane >> 4;
    const int m0 = blockIdx.y * BM, n0 = blockIdx.x * BN;
    const int wavebase = (tid & ~63);

    f32x4 acc[MT][NT] = {};

    for (int k0 = 0; k0 < K; k0 += 32) {
        #pragma unroll
        for (int r = 0; r < BM * 4; r += 256) {
            int c = r + tid;
            const bf16* g = A + (size_t)(m0 + (c >> 2)) * K + k0 + (c & 3) * 8;
            bf16* l = As + (size_t)(r + wavebase) * 8;
            __builtin_amdgcn_global_load_lds(
                (const __attribute__((address_space(1))) void*)g,
                (__attribute__((address_space(3))) void*)l, 16, 0, 0);
        }
        #pragma unroll
        for (int r = 0; r < BN * 4; r += 256) {
            int c = r + tid;
            const bf16* g = W + (size_t)(n0 + (c >> 2)) * K + k0 + (c & 3) * 8;
            bf16* l = Bs + (size_t)(r + wavebase) * 8;
            __builtin_amdgcn_global_load_lds(
                (const __attribute__((address_space(1))) void*)g,
                (__attribute__((address_space(3))) void*)l, 16, 0, 0);
        }
        __syncthreads();

        short8 af[MT], bfr[NT];
        #pragma unroll
        for (int i = 0; i < MT; i++)
            af[i] = *(const short8*)&As[(wm * WMx + i * 16 + r16) * 32 + quad * 8];
        #pragma unroll
        for (int j = 0; j < NT; j++)
            bfr[j] = *(const short8*)&Bs[(wn * WNx + j * 16 + r16) * 32 + quad * 8];
        #pragma unroll
        for (int i = 0; i < MT; i++)
            #pragma unroll
            for (int j = 0; j < NT; j++)
                acc[i][j] = __builtin_amdgcn_mfma_f32_16x16x32_bf16(
                    af[i], bfr[j], acc[i][j], 0, 0, 0);
        __syncthreads();
    }

    #pragma unroll
    for (int i = 0; i < MT; i++) {
        #pragma unroll
        for (int r = 0; r < 4; r++) {
            int m = m0 + wm * WMx + i * 16 + quad * 4 + r;
            int mo = m;
            if (flipC) { int b = m / L_; int l = m % L_; mo = b * L_ + (L_ - 1 - l); }
            #pragma unroll
            for (int j = 0; j < NT; j++) {
                int n = n0 + wn * WNx + j * 16 + r16;
                float v = acc[i][j][r];
                float* p = &C[(size_t)mo * ldc + n];
                if (EPI == 2) v += *p;
                *p = v;
            }
        }
    }
}

// ---------------- casts ----------------
__global__ __launch_bounds__(256)
void cast_kernel(const float* __restrict__ in, bf16* __restrict__ out, int n4)
{
    int i = blockIdx.x * 256 + threadIdx.x;
    if (i >= n4) return;
    float4 v = ((const float4*)in)[i];
    ushort4 o; o.x = f2bf(v.x); o.y = f2bf(v.y); o.z = f2bf(v.z); o.w = f2bf(v.w);
    ((ushort4*)out)[i] = o;
}

__global__ __launch_bounds__(256)
void cast_flip_kernel(const float* __restrict__ in, bf16* __restrict__ out, int flip)
{
    int i = blockIdx.x * 256 + threadIdx.x;        // over B*L*DM/4
    int k4 = i & (DM / 4 - 1); int m = i / (DM / 4);
    int b = m / L_, l = m % L_;
    int src = flip ? (b * L_ + (L_ - 1 - l)) : m;
    float4 v = ((const float4*)(in + (size_t)src * DM))[k4];
    ushort4 o; o.x = f2bf(v.x); o.y = f2bf(v.y); o.z = f2bf(v.z); o.w = f2bf(v.w);
    ((ushort4*)(out + (size_t)m * DM))[k4] = o;
}

// ---------------- conv + silu ----------------
__global__ __launch_bounds__(256)
void conv_silu_kernel(const float* __restrict__ xz, const float* __restrict__ conv_w,
                      const float* __restrict__ conv_b, float* __restrict__ xc)
{
    int idx = blockIdx.x * 256 + threadIdx.x;
    int d = idx % DI; int bl = idx / DI; int l = bl % L_; int b = bl / L_;
    float acc = conv_b[d];
    #pragma unroll
    for (int k = 0; k < DC; k++) {
        int ls = l + k - (DC - 1);
        if (ls >= 0)
            acc += xz[(size_t)(b * L_ + ls) * (2 * DI) + d] * conv_w[d * DC + k];
    }
    xc[idx] = acc / (1.f + expf(-acc));
}

// ---------------- chunk-parallel selective scan ----------------
__global__ __launch_bounds__(256)
void scan_phaseA(const float* __restrict__ dbl, const float* __restrict__ xc,
                 const float* __restrict__ dts, const float* __restrict__ A_log,
                 float* __restrict__ Pbuf, float* __restrict__ Hbuf)
{
    int t = blockIdx.x * 256 + threadIdx.x;
    int n = t & 15;
    int c = (t >> 4) & (NC - 1);
    int d = (t >> 9) & (DI - 1);
    int b = t >> 20;
    float Aval = -expf(A_log[d * DS + n]);
    float P = 1.f, H = 0.f;
    int l0 = c * CL;
    for (int i = 0; i < CL; i++) {
        size_t ro = (size_t)(b * L_ + l0 + i);
        float dt = dts[ro * DI + d];
        float x  = xc[ro * DI + d];
        float Bn = dbl[ro * GG + RK + n];
        float dA = expf(dt * Aval);
        P *= dA;
        H = dA * H + dt * x * Bn;
    }
    Pbuf[t] = P;
    Hbuf[t] = H;
}

__global__ __launch_bounds__(256)
void scan_phaseB(const float* __restrict__ Pbuf, float* __restrict__ Hbuf)
{
    int t = blockIdx.x * 256 + threadIdx.x;   // (b*DI+d)*DS + n
    int n = t & 15; int bd = t >> 4;
    size_t base = (size_t)bd * NC * DS + n;
    float run = 0.f;
    for (int c = 0; c < NC; c++) {
        size_t idx = base + (size_t)c * DS;
        float P  = Pbuf[idx];
        float Hl = Hbuf[idx];
        Hbuf[idx] = run;
        run = Hl + P * run;
    }
}

__global__ __launch_bounds__(256)
void scan_phaseC(const float* __restrict__ dbl, const float* __restrict__ xc,
                 float* __restrict__ dtys, const float* __restrict__ xz,
                 const float* __restrict__ A_log, const float* __restrict__ Dp,
                 const float* __restrict__ Hbuf)
{
    int t = blockIdx.x * 256 + threadIdx.x;
    int lane = t & 63; int w = t >> 6;
    int n = lane & 15, dsub = lane >> 4;
    int c = w & (NC - 1);
    int dgrp = (w >> 5) & 511;
    int b = w >> 14;
    int d = dgrp * 4 + dsub;

    float Aval = -expf(A_log[d * DS + n]);
    float Dval = Dp[d];
    float h = Hbuf[((size_t)(b * DI + d) * NC + c) * DS + n];
    int l0 = c * CL;

    for (int i = 0; i < CL; i++) {
        size_t ro = (size_t)(b * L_ + l0 + i);
        float dt = dtys[ro * DI + d];
        float x  = xc[ro * DI + d];
        float Bn = dbl[ro * GG + RK + n];
        float Cn = dbl[ro * GG + RK + DS + n];
        float dA = expf(dt * Aval);
        h = dA * h + dt * x * Bn;
        float cc = h * Cn;
        cc += __shfl_xor(cc, 8, 16);
        cc += __shfl_xor(cc, 4, 16);
        cc += __shfl_xor(cc, 2, 16);
        cc += __shfl_xor(cc, 1, 16);
        if (n == 0) {
            float z = xz[ro * (2 * DI) + DI + d];
            dtys[ro * DI + d] = (cc + x * Dval) * (z / (1.f + expf(-z)));
        }
    }
}

// Fallback single-pass scan
__global__ __launch_bounds__(256)
void scan_kernel(const float* __restrict__ dbl, const float* __restrict__ xc,
                 float* __restrict__ dtys, const float* __restrict__ xz,
                 const float* __restrict__ A_log, const float* __restrict__ Dp)
{
    int t = blockIdx.x * 256 + threadIdx.x;
    int lane = t & 63; int w = t >> 6;
    int n = lane & 15; int dsub = lane >> 4;
    int b = w / (DI / 4); int dgrp = w % (DI / 4);
    int d = dgrp * 4 + dsub;

    float Aval = -expf(A_log[d * DS + n]);
    float Dval = Dp[d];
    float h = 0.f;
    const float* dblb = dbl + (size_t)(b * L_) * GG;

    for (int l = 0; l < L_; l++) {
        size_t ro = (size_t)(b * L_ + l);
        float dt = dtys[ro * DI + d];
        float x  = xc[ro * DI + d];
        float Bn = dblb[l * GG + RK + n];
        float Cn = dblb[l * GG + RK + DS + n];
        float dA = expf(dt * Aval);
        h = dA * h + dt * x * Bn;
        float c = h * Cn;
        c += __shfl_xor(c, 8, 16);
        c += __shfl_xor(c, 4, 16);
        c += __shfl_xor(c, 2, 16);
        c += __shfl_xor(c, 1, 16);
        if (n == 0) {
            float z = xz[ro * (2 * DI) + DI + d];
            dtys[ro * DI + d] = (c + x * Dval) * (z / (1.f + expf(-z)));
        }
    }
}

__global__ __launch_bounds__(256)
void ln_kernel(const float* __restrict__ yo, const float* __restrict__ gamma,
               const float* __restrict__ beta, float* __restrict__ out)
{
    int row = blockIdx.x;
    const float* r = yo + (size_t)row * DM;
    float s = 0.f, s2 = 0.f;
    for (int i = threadIdx.x; i < DM; i += 256) { float v = r[i]; s += v; s2 += v * v; }
    #pragma unroll
    for (int o = 32; o > 0; o >>= 1) { s += __shfl_down(s, o); s2 += __shfl_down(s2, o); }
    __shared__ float sw[4], sw2[4];
    int wid = threadIdx.x >> 6, ln = threadIdx.x & 63;
    if (ln == 0) { sw[wid] = s; sw2[wid] = s2; }
    __syncthreads();
    if (threadIdx.x == 0) {
        float a = 0.f, b2 = 0.f;
        for (int i = 0; i < 4; i++) { a += sw[i]; b2 += sw2[i]; }
        sw[0] = a; sw2[0] = b2;
    }
    __syncthreads();
    float mean = sw[0] / DM;
    float var  = sw2[0] / DM - mean * mean;
    float rstd = rsqrtf(var + LN_EPS);
    for (int i = threadIdx.x; i < DM; i += 256) {
        float v = (r[i] - mean) * rstd;
        out[(size_t)row * DM + i] = gamma[i] * v + beta[i];
    }
}

extern "C" void kernel_launch(void* const* d_in, const int* in_sizes, int n_in,
                              void* d_out, int out_size, void* d_ws, size_t ws_size,
                              hipStream_t stream)
{
    const float* x = (const float*)d_in[0];

    float* ws  = (float*)d_ws;
    float* xz  = ws;                                  // B*L*2*DI = 8,388,608 f
    float* xc  = xz  + (size_t)B_ * L_ * 2 * DI;      // B*L*DI   = 4,194,304 f
    float* dbl = xc  + (size_t)B_ * L_ * DI;          // B*L*GG   =   196,608 f
    float* dt  = dbl + (size_t)B_ * L_ * GG;          // B*L*DI   = 4,194,304 f (becomes ys)
    float* yo  = dt  + (size_t)B_ * L_ * DI;          // B*L*DM   = 2,097,152 f
    float* Pb  = yo  + (size_t)B_ * L_ * DM;          // 2,097,152 f
    float* Hb  = Pb  + (size_t)B_ * DI * NC * DS;     // 2,097,152 f
    float* endf = Hb + (size_t)B_ * DI * NC * DS;
    const size_t need_base = (size_t)(endf - ws) * 4;
    bf16* wbf   = (bf16*)endf;                        // 4M bf16 = 8 MB
    bf16* actbf = wbf + (size_t)4 * 1024 * 1024;      // 4M bf16 = 8 MB
    const size_t need_mfma = need_base + 2 * (size_t)4 * 1024 * 1024 * 2;
    const int use_chunked = (ws_size >= need_base);
    const int use_mfma    = (ws_size >= need_mfma);

    dim3 blk(16, 16);
    const int M = B_ * L_;

    for (int dir = 0; dir < 2; dir++) {
        const float* in_proj   = (const float*)d_in[1 + dir * 9 + 0];
        const float* conv_w    = (const float*)d_in[1 + dir * 9 + 1];
        const float* conv_b    = (const float*)d_in[1 + dir * 9 + 2];
        const float* x_proj    = (const float*)d_in[1 + dir * 9 + 3];
        const float* dt_proj_w = (const float*)d_in[1 + dir * 9 + 4];
        const float* dt_proj_b = (const float*)d_in[1 + dir * 9 + 5];
        const float* A_log     = (const float*)d_in[1 + dir * 9 + 6];
        const float* Dp        = (const float*)d_in[1 + dir * 9 + 7];
        const float* out_proj  = (const float*)d_in[1 + dir * 9 + 8];

        // GEMM1: xz = x(flip?) @ in_proj^T            M x 4096, K=1024
        if (use_mfma) {
            cast_kernel<<<(2 * DI * DM / 4) / 256, 256, 0, stream>>>(in_proj, wbf, 2 * DI * DM / 4);
            cast_flip_kernel<<<(M * DM / 4) / 256, 256, 0, stream>>>(x, actbf, dir);
            dim3 g1(2 * DI / 128, M / 128);
            gemm_mfma<128, 128, 0><<<g1, 256, 0, stream>>>(actbf, wbf, xz, 2 * DI, DM, 0);
        } else {
            dim3 g1((2 * DI) / 64, M / 64);
            gemm_bt<0><<<g1, blk, 0, stream>>>(
                x, DM, in_proj, DM, xz, 2 * DI, M, 2 * DI, DM, dir, 0, nullptr);
        }

        // conv + silu
        conv_silu_kernel<<<(B_ * L_ * DI) / 256, 256, 0, stream>>>(xz, conv_w, conv_b, xc);

        // GEMM2: dbl = xc @ x_proj^T                  M x 96, K=2048
        dim3 g2((GG + 63) / 64, M / 64);
        gemm_bt<0><<<g2, blk, 0, stream>>>(
            xc, DI, x_proj, DI, dbl, GG, M, GG, DI, 0, 0, nullptr);

        // GEMM3: dt = softplus(dbl[:, :64] @ dt_proj_w^T + b)   M x 2048, K=64
        dim3 g3(DI / 64, M / 64);
        gemm_bt<1><<<g3, blk, 0, stream>>>(
            dbl, GG, dt_proj_w, RK, dt, DI, M, DI, RK, 0, 0, dt_proj_b);

        // selective scan + D-skip + z-gating (ys written into dt buffer)
        if (use_chunked) {
            scan_phaseA<<<(B_ * DI * NC * DS) / 256, 256, 0, stream>>>(
                dbl, xc, dt, A_log, Pb, Hb);
            scan_phaseB<<<(B_ * DI * DS) / 256, 256, 0, stream>>>(Pb, Hb);
            scan_phaseC<<<(B_ * (DI / 4) * NC * 64) / 256, 256, 0, stream>>>(
                dbl, xc, dt, xz, A_log, Dp, Hb);
        } else {
            scan_kernel<<<256, 256, 0, stream>>>(dbl, xc, dt, xz, A_log, Dp);
        }

        // GEMM4: yo (+)= ys @ out_proj^T              M x 1024, K=2048
        if (use_mfma) {
            cast_kernel<<<(DM * DI / 4) / 256, 256, 0, stream>>>(out_proj, wbf, DM * DI / 4);
            cast_kernel<<<(M * DI / 4) / 256, 256, 0, stream>>>(dt, actbf, M * DI / 4);
            dim3 g4(DM / 64, M / 128);
            if (dir == 0)
                gemm_mfma<128, 64, 0><<<g4, 256, 0, stream>>>(actbf, wbf, yo, DM, DI, 0);
            else
                gemm_mfma<128, 64, 2><<<g4, 256, 0, stream>>>(actbf, wbf, yo, DM, DI, 1);
        } else {
            dim3 g4(DM / 64, M / 64);
            if (dir == 0)
                gemm_bt<0><<<g4, blk, 0, stream>>>(
                    dt, DI, out_proj, DI, yo, DM, M, DM, DI, 0, 0, nullptr);
            else
                gemm_bt<2><<<g4, blk, 0, stream>>>(
                    dt, DI, out_proj, DI, yo, DM, M, DM, DI, 0, 1, nullptr);
        }
    }

    ln_kernel<<<B_ * L_, 256, 0, stream>>>(
        yo, (const float*)d_in[19], (const float*)d_in[20], (float*)d_out);
}

// Round 6
// 798.848 us; speedup vs baseline: 5.1752x; 1.8233x over previous
//
#include <hip/hip_runtime.h>
#include <hip/hip_bf16.h>
#include <math.h>

#define B_  2
#define L_  1024
#define DM  1024
#define DI  2048
#define DS  16
#define DC  4
#define RK  64
#define GG  96      // RK + 2*DS
#define NC  32      // scan chunks
#define CL  32      // L_/NC
#define LN_EPS 1e-5f

using bf16 = __hip_bfloat16;
typedef __attribute__((ext_vector_type(8))) short short8;
typedef __attribute__((ext_vector_type(4))) float f32x4;

__device__ __forceinline__ unsigned short f2bf(float f) {
    union { float f; unsigned u; } x; x.f = f;
    unsigned r = x.u + 0x7fffu + ((x.u >> 16) & 1u);   // round-to-nearest-even
    return (unsigned short)(r >> 16);
}

// ---------------- fp32 fallback / small GEMM ----------------
// C[M x N] = A[M x K] * W[N x K]^T ; EPI: 0 store, 1 bias+softplus, 2 read-add
template<int EPI>
__global__ __launch_bounds__(256)
void gemm_bt(const float* __restrict__ A, int lda,
             const float* __restrict__ W, int ldw,
             float* __restrict__ C, int ldc,
             int M, int N, int K, int flipA, int flipC,
             const float* __restrict__ bias)
{
    __shared__ float As[16][65];
    __shared__ float Ws[16][65];
    const int m0 = blockIdx.y * 64;
    const int n0 = blockIdx.x * 64;
    const int tx = threadIdx.x, ty = threadIdx.y;
    const int tid = ty * 16 + tx;
    float acc[4][4] = {};

    for (int k0 = 0; k0 < K; k0 += 16) {
        for (int e = tid; e < 1024; e += 256) {
            int mm = e >> 4, kk = e & 15;
            int gm = m0 + mm, gk = k0 + kk;
            float va = 0.f;
            if (gm < M && gk < K) {
                int pr = gm;
                if (flipA) { int b = gm / L_; int l = gm % L_; pr = b * L_ + (L_ - 1 - l); }
                va = A[(size_t)pr * lda + gk];
            }
            As[kk][mm] = va;
            int gn = n0 + mm;
            float vw = 0.f;
            if (gn < N && gk < K) vw = W[(size_t)gn * ldw + gk];
            Ws[kk][mm] = vw;
        }
        __syncthreads();
        #pragma unroll
        for (int k = 0; k < 16; k++) {
            float a[4], w[4];
            #pragma unroll
            for (int i = 0; i < 4; i++) a[i] = As[k][ty * 4 + i];
            #pragma unroll
            for (int j = 0; j < 4; j++) w[j] = Ws[k][tx * 4 + j];
            #pragma unroll
            for (int i = 0; i < 4; i++)
                #pragma unroll
                for (int j = 0; j < 4; j++) acc[i][j] += a[i] * w[j];
        }
        __syncthreads();
    }

    #pragma unroll
    for (int i = 0; i < 4; i++) {
        int m = m0 + ty * 4 + i;
        if (m >= M) continue;
        int mo = m;
        if (flipC) { int b = m / L_; int l = m % L_; mo = b * L_ + (L_ - 1 - l); }
        #pragma unroll
        for (int j = 0; j < 4; j++) {
            int n = n0 + tx * 4 + j;
            if (n >= N) continue;
            float v = acc[i][j];
            if (EPI == 1) { v += bias[n]; v = (v > 20.f) ? v : log1pf(expf(v)); }
            float* p = &C[(size_t)mo * ldc + n];
            if (EPI == 2) v += *p;
            *p = v;
        }
    }
}

// ---------------- bf16 MFMA GEMM (m97 structure) ----------------
// C[M x N] = A[M x K](bf16, row-major) * W[N x K]^T(bf16, row-major), fp32 out.
template<int BM, int BN, int EPI>
__global__ __launch_bounds__(256)
void gemm_mfma(const bf16* __restrict__ A, const bf16* __restrict__ W,
               float* __restrict__ C, int ldc, int K, int flipC)
{
    constexpr int WMx = BM / 2, WNx = BN / 2, MT = WMx / 16, NT = WNx / 16;
    __shared__ __align__(16) bf16 As[BM * 32];
    __shared__ __align__(16) bf16 Bs[BN * 32];
    const int tid  = threadIdx.x;
    const int lane = tid & 63;
    const int wave = tid >> 6;
    const int wm = wave >> 1, wn = wave & 1;
    const int r16 = lane & 15, quad = lane >> 4;
    const int m0 = blockIdx.y * BM, n0 = blockIdx.x * BN;
    const int wavebase = (tid & ~63);

    f32x4 acc[MT][NT] = {};

    for (int k0 = 0; k0 < K; k0 += 32) {
        #pragma unroll
        for (int r = 0; r < BM * 4; r += 256) {
            int c = r + tid;
            const bf16* g = A + (size_t)(m0 + (c >> 2)) * K + k0 + (c & 3) * 8;
            bf16* l = As + (size_t)(r + wavebase) * 8;
            __builtin_amdgcn_global_load_lds(
                (const __attribute__((address_space(1))) void*)g,
                (__attribute__((address_space(3))) void*)l, 16, 0, 0);
        }
        #pragma unroll
        for (int r = 0; r < BN * 4; r += 256) {
            int c = r + tid;
            const bf16* g = W + (size_t)(n0 + (c >> 2)) * K + k0 + (c & 3) * 8;
            bf16* l = Bs + (size_t)(r + wavebase) * 8;
            __builtin_amdgcn_global_load_lds(
                (const __attribute__((address_space(1))) void*)g,
                (__attribute__((address_space(3))) void*)l, 16, 0, 0);
        }
        __syncthreads();

        short8 af[MT], bfr[NT];
        #pragma unroll
        for (int i = 0; i < MT; i++)
            af[i] = *(const short8*)&As[(wm * WMx + i * 16 + r16) * 32 + quad * 8];
        #pragma unroll
        for (int j = 0; j < NT; j++)
            bfr[j] = *(const short8*)&Bs[(wn * WNx + j * 16 + r16) * 32 + quad * 8];
        #pragma unroll
        for (int i = 0; i < MT; i++)
            #pragma unroll
            for (int j = 0; j < NT; j++)
                acc[i][j] = __builtin_amdgcn_mfma_f32_16x16x32_bf16(
                    af[i], bfr[j], acc[i][j], 0, 0, 0);
        __syncthreads();
    }

    #pragma unroll
    for (int i = 0; i < MT; i++) {
        #pragma unroll
        for (int r = 0; r < 4; r++) {
            int m = m0 + wm * WMx + i * 16 + quad * 4 + r;
            int mo = m;
            if (flipC) { int b = m / L_; int l = m % L_; mo = b * L_ + (L_ - 1 - l); }
            #pragma unroll
            for (int j = 0; j < NT; j++) {
                int n = n0 + wn * WNx + j * 16 + r16;
                float v = acc[i][j][r];
                float* p = &C[(size_t)mo * ldc + n];
                if (EPI == 2) v += *p;
                *p = v;
            }
        }
    }
}

// ---------------- GEMM2 MFMA: M x 96, split-K, atomic accumulate ----------------
// A[M x K] bf16, W[96 x K] bf16, C[M x 96] fp32 (must be zeroed before launch).
template<int SPLITK>
__global__ __launch_bounds__(256)
void gemm2_mfma(const bf16* __restrict__ A, const bf16* __restrict__ W,
                float* __restrict__ C, int K)
{
    constexpr int BM = 128, BN = 96;
    constexpr int WMx = 64, WNx = 48, MT = 4, NT = 3;
    __shared__ __align__(16) bf16 As[BM * 32];
    __shared__ __align__(16) bf16 Bs[BN * 32];
    const int tid  = threadIdx.x;
    const int lane = tid & 63;
    const int wave = tid >> 6;
    const int wm = wave >> 1, wn = wave & 1;
    const int r16 = lane & 15, quad = lane >> 4;
    const int m0 = blockIdx.y * BM;
    const int wavebase = (tid & ~63);
    const int kper = K / SPLITK;
    const int kbeg = blockIdx.z * kper;

    f32x4 acc[MT][NT] = {};

    for (int kk = 0; kk < kper; kk += 32) {
        int k0 = kbeg + kk;
        #pragma unroll
        for (int r = 0; r < BM * 4; r += 256) {
            int c = r + tid;
            const bf16* g = A + (size_t)(m0 + (c >> 2)) * K + k0 + (c & 3) * 8;
            bf16* l = As + (size_t)(r + wavebase) * 8;
            __builtin_amdgcn_global_load_lds(
                (const __attribute__((address_space(1))) void*)g,
                (__attribute__((address_space(3))) void*)l, 16, 0, 0);
        }
        #pragma unroll
        for (int r = 0; r < BN * 4; r += 256) {
            if (r + wavebase < BN * 4) {          // wave-uniform guard (384 = 6 waves)
                int c = r + tid;
                const bf16* g = W + (size_t)(c >> 2) * K + k0 + (c & 3) * 8;
                bf16* l = Bs + (size_t)(r + wavebase) * 8;
                __builtin_amdgcn_global_load_lds(
                    (const __attribute__((address_space(1))) void*)g,
                    (__attribute__((address_space(3))) void*)l, 16, 0, 0);
            }
        }
        __syncthreads();

        short8 af[MT], bfr[NT];
        #pragma unroll
        for (int i = 0; i < MT; i++)
            af[i] = *(const short8*)&As[(wm * WMx + i * 16 + r16) * 32 + quad * 8];
        #pragma unroll
        for (int j = 0; j < NT; j++)
            bfr[j] = *(const short8*)&Bs[(wn * WNx + j * 16 + r16) * 32 + quad * 8];
        #pragma unroll
        for (int i = 0; i < MT; i++)
            #pragma unroll
            for (int j = 0; j < NT; j++)
                acc[i][j] = __builtin_amdgcn_mfma_f32_16x16x32_bf16(
                    af[i], bfr[j], acc[i][j], 0, 0, 0);
        __syncthreads();
    }

    #pragma unroll
    for (int i = 0; i < MT; i++) {
        #pragma unroll
        for (int r = 0; r < 4; r++) {
            int m = m0 + wm * WMx + i * 16 + quad * 4 + r;
            #pragma unroll
            for (int j = 0; j < NT; j++) {
                int n = wn * WNx + j * 16 + r16;
                atomicAdd(&C[(size_t)m * GG + n], acc[i][j][r]);
            }
        }
    }
}

// ---------------- casts ----------------
__global__ __launch_bounds__(256)
void cast_kernel(const float* __restrict__ in, bf16* __restrict__ out, int n4)
{
    int i = blockIdx.x * 256 + threadIdx.x;
    if (i >= n4) return;
    float4 v = ((const float4*)in)[i];
    ushort4 o; o.x = f2bf(v.x); o.y = f2bf(v.y); o.z = f2bf(v.z); o.w = f2bf(v.w);
    ((ushort4*)out)[i] = o;
}

__global__ __launch_bounds__(256)
void cast_flip_kernel(const float* __restrict__ in, bf16* __restrict__ out, int flip)
{
    int i = blockIdx.x * 256 + threadIdx.x;        // over B*L*DM/4
    int k4 = i & (DM / 4 - 1); int m = i / (DM / 4);
    int b = m / L_, l = m % L_;
    int src = flip ? (b * L_ + (L_ - 1 - l)) : m;
    float4 v = ((const float4*)(in + (size_t)src * DM))[k4];
    ushort4 o; o.x = f2bf(v.x); o.y = f2bf(v.y); o.z = f2bf(v.z); o.w = f2bf(v.w);
    ((ushort4*)(out + (size_t)m * DM))[k4] = o;
}

// ---------------- conv + silu ----------------
__global__ __launch_bounds__(256)
void conv_silu_kernel(const float* __restrict__ xz, const float* __restrict__ conv_w,
                      const float* __restrict__ conv_b, float* __restrict__ xc)
{
    int idx = blockIdx.x * 256 + threadIdx.x;
    int d = idx % DI; int bl = idx / DI; int l = bl % L_; int b = bl / L_;
    float acc = conv_b[d];
    #pragma unroll
    for (int k = 0; k < DC; k++) {
        int ls = l + k - (DC - 1);
        if (ls >= 0)
            acc += xz[(size_t)(b * L_ + ls) * (2 * DI) + d] * conv_w[d * DC + k];
    }
    xc[idx] = acc / (1.f + expf(-acc));
}

// ---------------- chunk-parallel selective scan ----------------
__global__ __launch_bounds__(256)
void scan_phaseA(const float* __restrict__ dbl, const float* __restrict__ xc,
                 const float* __restrict__ dts, const float* __restrict__ A_log,
                 float* __restrict__ Pbuf, float* __restrict__ Hbuf)
{
    int t = blockIdx.x * 256 + threadIdx.x;
    int n = t & 15;
    int c = (t >> 4) & (NC - 1);
    int d = (t >> 9) & (DI - 1);
    int b = t >> 20;
    float Aval = -expf(A_log[d * DS + n]);
    float P = 1.f, H = 0.f;
    int l0 = c * CL;
    for (int i = 0; i < CL; i++) {
        size_t ro = (size_t)(b * L_ + l0 + i);
        float dt = dts[ro * DI + d];
        float x  = xc[ro * DI + d];
        float Bn = dbl[ro * GG + RK + n];
        float dA = expf(dt * Aval);
        P *= dA;
        H = dA * H + dt * x * Bn;
    }
    Pbuf[t] = P;
    Hbuf[t] = H;
}

__global__ __launch_bounds__(256)
void scan_phaseB(const float* __restrict__ Pbuf, float* __restrict__ Hbuf)
{
    int t = blockIdx.x * 256 + threadIdx.x;   // (b*DI+d)*DS + n
    int n = t & 15; int bd = t >> 4;
    size_t base = (size_t)bd * NC * DS + n;
    float run = 0.f;
    for (int c = 0; c < NC; c++) {
        size_t idx = base + (size_t)c * DS;
        float P  = Pbuf[idx];
        float Hl = Hbuf[idx];
        Hbuf[idx] = run;
        run = Hl + P * run;
    }
}

__global__ __launch_bounds__(256)
void scan_phaseC(const float* __restrict__ dbl, const float* __restrict__ xc,
                 float* __restrict__ dtys, const float* __restrict__ xz,
                 const float* __restrict__ A_log, const float* __restrict__ Dp,
                 const float* __restrict__ Hbuf)
{
    int t = blockIdx.x * 256 + threadIdx.x;
    int lane = t & 63; int w = t >> 6;
    int n = lane & 15, dsub = lane >> 4;
    int c = w & (NC - 1);
    int dgrp = (w >> 5) & 511;
    int b = w >> 14;
    int d = dgrp * 4 + dsub;

    float Aval = -expf(A_log[d * DS + n]);
    float Dval = Dp[d];
    float h = Hbuf[((size_t)(b * DI + d) * NC + c) * DS + n];
    int l0 = c * CL;

    for (int i = 0; i < CL; i++) {
        size_t ro = (size_t)(b * L_ + l0 + i);
        float dt = dtys[ro * DI + d];
        float x  = xc[ro * DI + d];
        float Bn = dbl[ro * GG + RK + n];
        float Cn = dbl[ro * GG + RK + DS + n];
        float dA = expf(dt * Aval);
        h = dA * h + dt * x * Bn;
        float cc = h * Cn;
        cc += __shfl_xor(cc, 8, 16);
        cc += __shfl_xor(cc, 4, 16);
        cc += __shfl_xor(cc, 2, 16);
        cc += __shfl_xor(cc, 1, 16);
        if (n == 0) {
            float z = xz[ro * (2 * DI) + DI + d];
            dtys[ro * DI + d] = (cc + x * Dval) * (z / (1.f + expf(-z)));
        }
    }
}

// Fallback single-pass scan
__global__ __launch_bounds__(256)
void scan_kernel(const float* __restrict__ dbl, const float* __restrict__ xc,
                 float* __restrict__ dtys, const float* __restrict__ xz,
                 const float* __restrict__ A_log, const float* __restrict__ Dp)
{
    int t = blockIdx.x * 256 + threadIdx.x;
    int lane = t & 63; int w = t >> 6;
    int n = lane & 15; int dsub = lane >> 4;
    int b = w / (DI / 4); int dgrp = w % (DI / 4);
    int d = dgrp * 4 + dsub;

    float Aval = -expf(A_log[d * DS + n]);
    float Dval = Dp[d];
    float h = 0.f;
    const float* dblb = dbl + (size_t)(b * L_) * GG;

    for (int l = 0; l < L_; l++) {
        size_t ro = (size_t)(b * L_ + l);
        float dt = dtys[ro * DI + d];
        float x  = xc[ro * DI + d];
        float Bn = dblb[l * GG + RK + n];
        float Cn = dblb[l * GG + RK + DS + n];
        float dA = expf(dt * Aval);
        h = dA * h + dt * x * Bn;
        float c = h * Cn;
        c += __shfl_xor(c, 8, 16);
        c += __shfl_xor(c, 4, 16);
        c += __shfl_xor(c, 2, 16);
        c += __shfl_xor(c, 1, 16);
        if (n == 0) {
            float z = xz[ro * (2 * DI) + DI + d];
            dtys[ro * DI + d] = (c + x * Dval) * (z / (1.f + expf(-z)));
        }
    }
}

__global__ __launch_bounds__(256)
void ln_kernel(const float* __restrict__ yo, const float* __restrict__ gamma,
               const float* __restrict__ beta, float* __restrict__ out)
{
    int row = blockIdx.x;
    const float* r = yo + (size_t)row * DM;
    float s = 0.f, s2 = 0.f;
    for (int i = threadIdx.x; i < DM; i += 256) { float v = r[i]; s += v; s2 += v * v; }
    #pragma unroll
    for (int o = 32; o > 0; o >>= 1) { s += __shfl_down(s, o); s2 += __shfl_down(s2, o); }
    __shared__ float sw[4], sw2[4];
    int wid = threadIdx.x >> 6, ln = threadIdx.x & 63;
    if (ln == 0) { sw[wid] = s; sw2[wid] = s2; }
    __syncthreads();
    if (threadIdx.x == 0) {
        float a = 0.f, b2 = 0.f;
        for (int i = 0; i < 4; i++) { a += sw[i]; b2 += sw2[i]; }
        sw[0] = a; sw2[0] = b2;
    }
    __syncthreads();
    float mean = sw[0] / DM;
    float var  = sw2[0] / DM - mean * mean;
    float rstd = rsqrtf(var + LN_EPS);
    for (int i = threadIdx.x; i < DM; i += 256) {
        float v = (r[i] - mean) * rstd;
        out[(size_t)row * DM + i] = gamma[i] * v + beta[i];
    }
}

extern "C" void kernel_launch(void* const* d_in, const int* in_sizes, int n_in,
                              void* d_out, int out_size, void* d_ws, size_t ws_size,
                              hipStream_t stream)
{
    const float* x = (const float*)d_in[0];

    float* ws  = (float*)d_ws;
    float* xz  = ws;                                  // B*L*2*DI = 8,388,608 f
    float* xc  = xz  + (size_t)B_ * L_ * 2 * DI;      // B*L*DI   = 4,194,304 f
    float* dbl = xc  + (size_t)B_ * L_ * DI;          // B*L*GG   =   196,608 f
    float* dt  = dbl + (size_t)B_ * L_ * GG;          // B*L*DI   = 4,194,304 f (becomes ys)
    float* yo  = dt  + (size_t)B_ * L_ * DI;          // B*L*DM   = 2,097,152 f
    float* Pb  = yo  + (size_t)B_ * L_ * DM;          // 2,097,152 f
    float* Hb  = Pb  + (size_t)B_ * DI * NC * DS;     // 2,097,152 f
    float* endf = Hb + (size_t)B_ * DI * NC * DS;
    const size_t need_base = (size_t)(endf - ws) * 4;
    bf16* wbf   = (bf16*)endf;                        // 4M bf16 =  8 MB (max weight)
    bf16* actbf = wbf + (size_t)4 * 1024 * 1024;      // 8M bf16 = 16 MB (max activation)
    const size_t need_mfma = need_base + (4 + 8) * (size_t)1024 * 1024 * 2;
    const int use_chunked = (ws_size >= need_base);
    const int use_mfma    = (ws_size >= need_mfma);

    dim3 blk(16, 16);
    const int M = B_ * L_;

    for (int dir = 0; dir < 2; dir++) {
        const float* in_proj   = (const float*)d_in[1 + dir * 9 + 0];
        const float* conv_w    = (const float*)d_in[1 + dir * 9 + 1];
        const float* conv_b    = (const float*)d_in[1 + dir * 9 + 2];
        const float* x_proj    = (const float*)d_in[1 + dir * 9 + 3];
        const float* dt_proj_w = (const float*)d_in[1 + dir * 9 + 4];
        const float* dt_proj_b = (const float*)d_in[1 + dir * 9 + 5];
        const float* A_log     = (const float*)d_in[1 + dir * 9 + 6];
        const float* Dp        = (const float*)d_in[1 + dir * 9 + 7];
        const float* out_proj  = (const float*)d_in[1 + dir * 9 + 8];

        // GEMM1: xz = x(flip?) @ in_proj^T            M x 4096, K=1024
        if (use_mfma) {
            cast_kernel<<<(2 * DI * DM / 4) / 256, 256, 0, stream>>>(in_proj, wbf, 2 * DI * DM / 4);
            cast_flip_kernel<<<(M * DM / 4) / 256, 256, 0, stream>>>(x, actbf, dir);
            dim3 g1(2 * DI / 128, M / 128);
            gemm_mfma<128, 128, 0><<<g1, 256, 0, stream>>>(actbf, wbf, xz, 2 * DI, DM, 0);
        } else {
            dim3 g1((2 * DI) / 64, M / 64);
            gemm_bt<0><<<g1, blk, 0, stream>>>(
                x, DM, in_proj, DM, xz, 2 * DI, M, 2 * DI, DM, dir, 0, nullptr);
        }

        // conv + silu
        conv_silu_kernel<<<(B_ * L_ * DI) / 256, 256, 0, stream>>>(xz, conv_w, conv_b, xc);

        // GEMM2: dbl = xc @ x_proj^T                  M x 96, K=2048
        if (use_mfma) {
            cast_kernel<<<(M * DI / 4) / 256, 256, 0, stream>>>(xc, actbf, M * DI / 4);
            cast_kernel<<<(GG * DI / 4 + 255) / 256, 256, 0, stream>>>(x_proj, wbf, GG * DI / 4);
            hipMemsetAsync(dbl, 0, (size_t)M * GG * sizeof(float), stream);
            dim3 g2(1, M / 128, 8);
            gemm2_mfma<8><<<g2, 256, 0, stream>>>(actbf, wbf, dbl, DI);
        } else {
            dim3 g2((GG + 63) / 64, M / 64);
            gemm_bt<0><<<g2, blk, 0, stream>>>(
                xc, DI, x_proj, DI, dbl, GG, M, GG, DI, 0, 0, nullptr);
        }

        // GEMM3: dt = softplus(dbl[:, :64] @ dt_proj_w^T + b)   M x 2048, K=64
        dim3 g3(DI / 64, M / 64);
        gemm_bt<1><<<g3, blk, 0, stream>>>(
            dbl, GG, dt_proj_w, RK, dt, DI, M, DI, RK, 0, 0, dt_proj_b);

        // selective scan + D-skip + z-gating (ys written into dt buffer)
        if (use_chunked) {
            scan_phaseA<<<(B_ * DI * NC * DS) / 256, 256, 0, stream>>>(
                dbl, xc, dt, A_log, Pb, Hb);
            scan_phaseB<<<(B_ * DI * DS) / 256, 256, 0, stream>>>(Pb, Hb);
            scan_phaseC<<<(B_ * (DI / 4) * NC * 64) / 256, 256, 0, stream>>>(
                dbl, xc, dt, xz, A_log, Dp, Hb);
        } else {
            scan_kernel<<<256, 256, 0, stream>>>(dbl, xc, dt, xz, A_log, Dp);
        }

        // GEMM4: yo (+)= ys @ out_proj^T              M x 1024, K=2048
        if (use_mfma) {
            cast_kernel<<<(DM * DI / 4) / 256, 256, 0, stream>>>(out_proj, wbf, DM * DI / 4);
            cast_kernel<<<(M * DI / 4) / 256, 256, 0, stream>>>(dt, actbf, M * DI / 4);
            dim3 g4(DM / 64, M / 128);
            if (dir == 0)
                gemm_mfma<128, 64, 0><<<g4, 256, 0, stream>>>(actbf, wbf, yo, DM, DI, 0);
            else
                gemm_mfma<128, 64, 2><<<g4, 256, 0, stream>>>(actbf, wbf, yo, DM, DI, 1);
        } else {
            dim3 g4(DM / 64, M / 64);
            if (dir == 0)
                gemm_bt<0><<<g4, blk, 0, stream>>>(
                    dt, DI, out_proj, DI, yo, DM, M, DM, DI, 0, 0, nullptr);
            else
                gemm_bt<2><<<g4, blk, 0, stream>>>(
                    dt, DI, out_proj, DI, yo, DM, M, DM, DI, 0, 1, nullptr);
        }
    }

    ln_kernel<<<B_ * L_, 256, 0, stream>>>(
        yo, (const float*)d_in[19], (const float*)d_in[20], (float*)d_out);
}

// Round 7
// 732.273 us; speedup vs baseline: 5.6457x; 1.0909x over previous
//
#include <hip/hip_runtime.h>
#include <hip/hip_bf16.h>
#include <math.h>

#define B_  2
#define L_  1024
#define DM  1024
#define DI  2048
#define DS  16
#define DC  4
#define RK  64
#define GG  96      // RK + 2*DS
#define NC  32      // scan chunks
#define CL  32      // L_/NC
#define LN_EPS 1e-5f

using bf16 = __hip_bfloat16;
typedef __attribute__((ext_vector_type(8))) short short8;
typedef __attribute__((ext_vector_type(4))) float f32x4;

__device__ __forceinline__ unsigned short f2bf(float f) {
    union { float f; unsigned u; } x; x.f = f;
    unsigned r = x.u + 0x7fffu + ((x.u >> 16) & 1u);   // round-to-nearest-even
    return (unsigned short)(r >> 16);
}

// ---------------- fp32 fallback / small GEMM ----------------
template<int EPI>
__global__ __launch_bounds__(256)
void gemm_bt(const float* __restrict__ A, int lda,
             const float* __restrict__ W, int ldw,
             float* __restrict__ C, int ldc,
             int M, int N, int K, int flipA, int flipC,
             const float* __restrict__ bias)
{
    __shared__ float As[16][65];
    __shared__ float Ws[16][65];
    const int m0 = blockIdx.y * 64;
    const int n0 = blockIdx.x * 64;
    const int tx = threadIdx.x, ty = threadIdx.y;
    const int tid = ty * 16 + tx;
    float acc[4][4] = {};

    for (int k0 = 0; k0 < K; k0 += 16) {
        for (int e = tid; e < 1024; e += 256) {
            int mm = e >> 4, kk = e & 15;
            int gm = m0 + mm, gk = k0 + kk;
            float va = 0.f;
            if (gm < M && gk < K) {
                int pr = gm;
                if (flipA) { int b = gm / L_; int l = gm % L_; pr = b * L_ + (L_ - 1 - l); }
                va = A[(size_t)pr * lda + gk];
            }
            As[kk][mm] = va;
            int gn = n0 + mm;
            float vw = 0.f;
            if (gn < N && gk < K) vw = W[(size_t)gn * ldw + gk];
            Ws[kk][mm] = vw;
        }
        __syncthreads();
        #pragma unroll
        for (int k = 0; k < 16; k++) {
            float a[4], w[4];
            #pragma unroll
            for (int i = 0; i < 4; i++) a[i] = As[k][ty * 4 + i];
            #pragma unroll
            for (int j = 0; j < 4; j++) w[j] = Ws[k][tx * 4 + j];
            #pragma unroll
            for (int i = 0; i < 4; i++)
                #pragma unroll
                for (int j = 0; j < 4; j++) acc[i][j] += a[i] * w[j];
        }
        __syncthreads();
    }

    #pragma unroll
    for (int i = 0; i < 4; i++) {
        int m = m0 + ty * 4 + i;
        if (m >= M) continue;
        int mo = m;
        if (flipC) { int b = m / L_; int l = m % L_; mo = b * L_ + (L_ - 1 - l); }
        #pragma unroll
        for (int j = 0; j < 4; j++) {
            int n = n0 + tx * 4 + j;
            if (n >= N) continue;
            float v = acc[i][j];
            if (EPI == 1) { v += bias[n]; v = (v > 20.f) ? v : log1pf(expf(v)); }
            float* p = &C[(size_t)mo * ldc + n];
            if (EPI == 2) v += *p;
            *p = v;
        }
    }
}

// ---------------- bf16 MFMA GEMM ----------------
// C[M x N] = A[M x K eff](row stride lda) * W[N x Keff]^T(row stride ldw), fp32 out.
// EPI: 0 store, 1 bias+softplus, 2 read-add(+flipC)
template<int BM, int BN, int EPI>
__global__ __launch_bounds__(256)
void gemm_mfma(const bf16* __restrict__ A, int lda,
               const bf16* __restrict__ W, int ldw,
               float* __restrict__ C, int ldc, int K, int flipC,
               const float* __restrict__ bias)
{
    constexpr int WMx = BM / 2, WNx = BN / 2, MT = WMx / 16, NT = WNx / 16;
    __shared__ __align__(16) bf16 As[BM * 32];
    __shared__ __align__(16) bf16 Bs[BN * 32];
    const int tid  = threadIdx.x;
    const int lane = tid & 63;
    const int wave = tid >> 6;
    const int wm = wave >> 1, wn = wave & 1;
    const int r16 = lane & 15, quad = lane >> 4;
    const int m0 = blockIdx.y * BM, n0 = blockIdx.x * BN;
    const int wavebase = (tid & ~63);

    f32x4 acc[MT][NT] = {};

    for (int k0 = 0; k0 < K; k0 += 32) {
        #pragma unroll
        for (int r = 0; r < BM * 4; r += 256) {
            int c = r + tid;
            const bf16* g = A + (size_t)(m0 + (c >> 2)) * lda + k0 + (c & 3) * 8;
            bf16* l = As + (size_t)(r + wavebase) * 8;
            __builtin_amdgcn_global_load_lds(
                (const __attribute__((address_space(1))) void*)g,
                (__attribute__((address_space(3))) void*)l, 16, 0, 0);
        }
        #pragma unroll
        for (int r = 0; r < BN * 4; r += 256) {
            int c = r + tid;
            const bf16* g = W + (size_t)(n0 + (c >> 2)) * ldw + k0 + (c & 3) * 8;
            bf16* l = Bs + (size_t)(r + wavebase) * 8;
            __builtin_amdgcn_global_load_lds(
                (const __attribute__((address_space(1))) void*)g,
                (__attribute__((address_space(3))) void*)l, 16, 0, 0);
        }
        __syncthreads();

        short8 af[MT], bfr[NT];
        #pragma unroll
        for (int i = 0; i < MT; i++)
            af[i] = *(const short8*)&As[(wm * WMx + i * 16 + r16) * 32 + quad * 8];
        #pragma unroll
        for (int j = 0; j < NT; j++)
            bfr[j] = *(const short8*)&Bs[(wn * WNx + j * 16 + r16) * 32 + quad * 8];
        #pragma unroll
        for (int i = 0; i < MT; i++)
            #pragma unroll
            for (int j = 0; j < NT; j++)
                acc[i][j] = __builtin_amdgcn_mfma_f32_16x16x32_bf16(
                    af[i], bfr[j], acc[i][j], 0, 0, 0);
        __syncthreads();
    }

    #pragma unroll
    for (int i = 0; i < MT; i++) {
        #pragma unroll
        for (int r = 0; r < 4; r++) {
            int m = m0 + wm * WMx + i * 16 + quad * 4 + r;
            int mo = m;
            if (flipC) { int b = m / L_; int l = m % L_; mo = b * L_ + (L_ - 1 - l); }
            #pragma unroll
            for (int j = 0; j < NT; j++) {
                int n = n0 + wn * WNx + j * 16 + r16;
                float v = acc[i][j][r];
                if (EPI == 1) {
                    v += bias[n];
                    v = (v > 20.f) ? v : __logf(1.f + __expf(v));
                }
                float* p = &C[(size_t)mo * ldc + n];
                if (EPI == 2) v += *p;
                *p = v;
            }
        }
    }
}

// ---------------- GEMM2 MFMA: M x 96, split-K, atomic accumulate ----------------
template<int SPLITK>
__global__ __launch_bounds__(256)
void gemm2_mfma(const bf16* __restrict__ A, const bf16* __restrict__ W,
                float* __restrict__ C, int K)
{
    constexpr int BM = 128, BN = 96;
    constexpr int WMx = 64, WNx = 48, MT = 4, NT = 3;
    __shared__ __align__(16) bf16 As[BM * 32];
    __shared__ __align__(16) bf16 Bs[BN * 32];
    const int tid  = threadIdx.x;
    const int lane = tid & 63;
    const int wave = tid >> 6;
    const int wm = wave >> 1, wn = wave & 1;
    const int r16 = lane & 15, quad = lane >> 4;
    const int m0 = blockIdx.y * BM;
    const int wavebase = (tid & ~63);
    const int kper = K / SPLITK;
    const int kbeg = blockIdx.z * kper;

    f32x4 acc[MT][NT] = {};

    for (int kk = 0; kk < kper; kk += 32) {
        int k0 = kbeg + kk;
        #pragma unroll
        for (int r = 0; r < BM * 4; r += 256) {
            int c = r + tid;
            const bf16* g = A + (size_t)(m0 + (c >> 2)) * K + k0 + (c & 3) * 8;
            bf16* l = As + (size_t)(r + wavebase) * 8;
            __builtin_amdgcn_global_load_lds(
                (const __attribute__((address_space(1))) void*)g,
                (__attribute__((address_space(3))) void*)l, 16, 0, 0);
        }
        #pragma unroll
        for (int r = 0; r < BN * 4; r += 256) {
            if (r + wavebase < BN * 4) {          // wave-uniform guard (384 = 6 waves)
                int c = r + tid;
                const bf16* g = W + (size_t)(c >> 2) * K + k0 + (c & 3) * 8;
                bf16* l = Bs + (size_t)(r + wavebase) * 8;
                __builtin_amdgcn_global_load_lds(
                    (const __attribute__((address_space(1))) void*)g,
                    (__attribute__((address_space(3))) void*)l, 16, 0, 0);
            }
        }
        __syncthreads();

        short8 af[MT], bfr[NT];
        #pragma unroll
        for (int i = 0; i < MT; i++)
            af[i] = *(const short8*)&As[(wm * WMx + i * 16 + r16) * 32 + quad * 8];
        #pragma unroll
        for (int j = 0; j < NT; j++)
            bfr[j] = *(const short8*)&Bs[(wn * WNx + j * 16 + r16) * 32 + quad * 8];
        #pragma unroll
        for (int i = 0; i < MT; i++)
            #pragma unroll
            for (int j = 0; j < NT; j++)
                acc[i][j] = __builtin_amdgcn_mfma_f32_16x16x32_bf16(
                    af[i], bfr[j], acc[i][j], 0, 0, 0);
        __syncthreads();
    }

    #pragma unroll
    for (int i = 0; i < MT; i++) {
        #pragma unroll
        for (int r = 0; r < 4; r++) {
            int m = m0 + wm * WMx + i * 16 + quad * 4 + r;
            #pragma unroll
            for (int j = 0; j < NT; j++) {
                int n = wn * WNx + j * 16 + r16;
                atomicAdd(&C[(size_t)m * GG + n], acc[i][j][r]);
            }
        }
    }
}

// ---------------- casts ----------------
__global__ __launch_bounds__(256)
void cast_kernel(const float* __restrict__ in, bf16* __restrict__ out, int n4)
{
    int i = blockIdx.x * 256 + threadIdx.x;
    if (i >= n4) return;
    float4 v = ((const float4*)in)[i];
    ushort4 o; o.x = f2bf(v.x); o.y = f2bf(v.y); o.z = f2bf(v.z); o.w = f2bf(v.w);
    ((ushort4*)out)[i] = o;
}

__global__ __launch_bounds__(256)
void cast_flip_kernel(const float* __restrict__ in, bf16* __restrict__ out, int flip)
{
    int i = blockIdx.x * 256 + threadIdx.x;        // over B*L*DM/4
    int k4 = i & (DM / 4 - 1); int m = i / (DM / 4);
    int b = m / L_, l = m % L_;
    int src = flip ? (b * L_ + (L_ - 1 - l)) : m;
    float4 v = ((const float4*)(in + (size_t)src * DM))[k4];
    ushort4 o; o.x = f2bf(v.x); o.y = f2bf(v.y); o.z = f2bf(v.z); o.w = f2bf(v.w);
    ((ushort4*)(out + (size_t)m * DM))[k4] = o;
}

// ---------------- conv + silu; also silu(z) in place over the z-half of xz ----
__global__ __launch_bounds__(256)
void conv_silu_kernel(float* __restrict__ xz, const float* __restrict__ conv_w,
                      const float* __restrict__ conv_b, float* __restrict__ xc)
{
    int idx = blockIdx.x * 256 + threadIdx.x;
    int d = idx % DI; int bl = idx / DI; int l = bl % L_; int b = bl / L_;
    float acc = conv_b[d];
    #pragma unroll
    for (int k = 0; k < DC; k++) {
        int ls = l + k - (DC - 1);
        if (ls >= 0)
            acc += xz[(size_t)(b * L_ + ls) * (2 * DI) + d] * conv_w[d * DC + k];
    }
    xc[idx] = acc / (1.f + __expf(-acc));
    size_t zi = (size_t)(b * L_ + l) * (2 * DI) + DI + d;
    float z = xz[zi];
    xz[zi] = z / (1.f + __expf(-z));
}

// ---------------- chunk-parallel selective scan ----------------
__global__ __launch_bounds__(256)
void scan_phaseA(const float* __restrict__ dbl, const float* __restrict__ xc,
                 const float* __restrict__ dts, const float* __restrict__ A_log,
                 float* __restrict__ Pbuf, float* __restrict__ Hbuf)
{
    int t = blockIdx.x * 256 + threadIdx.x;
    int n = t & 15;
    int c = (t >> 4) & (NC - 1);
    int d = (t >> 9) & (DI - 1);
    int b = t >> 20;
    float Aval = -__expf(A_log[d * DS + n]);
    float P = 1.f, H = 0.f;
    int l0 = c * CL;
    const float* pdt = dts + (size_t)(b * L_ + l0) * DI + d;
    const float* pxc = xc  + (size_t)(b * L_ + l0) * DI + d;
    const float* pB  = dbl + (size_t)(b * L_ + l0) * GG + RK + n;
    #pragma unroll 4
    for (int i = 0; i < CL; i++) {
        float dt = *pdt, x = *pxc, Bn = *pB;
        float dA = __expf(dt * Aval);
        P *= dA;
        H = dA * H + dt * x * Bn;
        pdt += DI; pxc += DI; pB += GG;
    }
    Pbuf[t] = P;
    Hbuf[t] = H;
}

__global__ __launch_bounds__(256)
void scan_phaseB(const float* __restrict__ Pbuf, float* __restrict__ Hbuf)
{
    int t = blockIdx.x * 256 + threadIdx.x;   // (b*DI+d)*DS + n
    int n = t & 15; int bd = t >> 4;
    size_t base = (size_t)bd * NC * DS + n;
    float run = 0.f;
    for (int c = 0; c < NC; c++) {
        size_t idx = base + (size_t)c * DS;
        float P  = Pbuf[idx];
        float Hl = Hbuf[idx];
        Hbuf[idx] = run;
        run = Hl + P * run;
    }
}

// Phase C: wave = (b, d-group-of-4, chunk); lanes = 16 n x 4 d.
// xz z-half already holds silu(z). Writes gated y into dtys.
__global__ __launch_bounds__(256)
void scan_phaseC(const float* __restrict__ dbl, const float* __restrict__ xc,
                 float* __restrict__ dtys, const float* __restrict__ xz,
                 const float* __restrict__ A_log, const float* __restrict__ Dp,
                 const float* __restrict__ Hbuf)
{
    int t = blockIdx.x * 256 + threadIdx.x;
    int lane = t & 63; int w = t >> 6;
    int n = lane & 15, dsub = lane >> 4;
    int c = w & (NC - 1);
    int dgrp = (w >> 5) & 511;
    int b = w >> 14;
    int d = dgrp * 4 + dsub;

    float Aval = -__expf(A_log[d * DS + n]);
    float Dval = Dp[d];
    float h = Hbuf[((size_t)(b * DI + d) * NC + c) * DS + n];
    int l0 = c * CL;

    const float* pdt = dtys + (size_t)(b * L_ + l0) * DI + d;
    float*       pot = dtys + (size_t)(b * L_ + l0) * DI + d;
    const float* pxc = xc   + (size_t)(b * L_ + l0) * DI + d;
    const float* pB  = dbl  + (size_t)(b * L_ + l0) * GG + RK + n;
    const float* psz = xz   + (size_t)(b * L_ + l0) * (2 * DI) + DI + d;

    #pragma unroll 4
    for (int i = 0; i < CL; i++) {
        float dt = *pdt, x = *pxc, Bn = *pB, Cn = pB[DS];
        float dA = __expf(dt * Aval);
        h = dA * h + dt * x * Bn;
        float cc = h * Cn;
        cc += __shfl_xor(cc, 8, 16);
        cc += __shfl_xor(cc, 4, 16);
        cc += __shfl_xor(cc, 2, 16);
        cc += __shfl_xor(cc, 1, 16);
        if (n == 0) *pot = (cc + x * Dval) * (*psz);
        pdt += DI; pot += DI; pxc += DI; pB += GG; psz += 2 * DI;
    }
}

// Fallback single-pass scan (xz z-half already silu'd)
__global__ __launch_bounds__(256)
void scan_kernel(const float* __restrict__ dbl, const float* __restrict__ xc,
                 float* __restrict__ dtys, const float* __restrict__ xz,
                 const float* __restrict__ A_log, const float* __restrict__ Dp)
{
    int t = blockIdx.x * 256 + threadIdx.x;
    int lane = t & 63; int w = t >> 6;
    int n = lane & 15; int dsub = lane >> 4;
    int b = w / (DI / 4); int dgrp = w % (DI / 4);
    int d = dgrp * 4 + dsub;

    float Aval = -__expf(A_log[d * DS + n]);
    float Dval = Dp[d];
    float h = 0.f;
    const float* dblb = dbl + (size_t)(b * L_) * GG;

    for (int l = 0; l < L_; l++) {
        size_t ro = (size_t)(b * L_ + l);
        float dt = dtys[ro * DI + d];
        float x  = xc[ro * DI + d];
        float Bn = dblb[l * GG + RK + n];
        float Cn = dblb[l * GG + RK + DS + n];
        float dA = __expf(dt * Aval);
        h = dA * h + dt * x * Bn;
        float c = h * Cn;
        c += __shfl_xor(c, 8, 16);
        c += __shfl_xor(c, 4, 16);
        c += __shfl_xor(c, 2, 16);
        c += __shfl_xor(c, 1, 16);
        if (n == 0) {
            float sz = xz[ro * (2 * DI) + DI + d];
            dtys[ro * DI + d] = (c + x * Dval) * sz;
        }
    }
}

__global__ __launch_bounds__(256)
void ln_kernel(const float* __restrict__ yo, const float* __restrict__ gamma,
               const float* __restrict__ beta, float* __restrict__ out)
{
    int row = blockIdx.x;
    const float* r = yo + (size_t)row * DM;
    float s = 0.f, s2 = 0.f;
    for (int i = threadIdx.x; i < DM; i += 256) { float v = r[i]; s += v; s2 += v * v; }
    #pragma unroll
    for (int o = 32; o > 0; o >>= 1) { s += __shfl_down(s, o); s2 += __shfl_down(s2, o); }
    __shared__ float sw[4], sw2[4];
    int wid = threadIdx.x >> 6, ln = threadIdx.x & 63;
    if (ln == 0) { sw[wid] = s; sw2[wid] = s2; }
    __syncthreads();
    if (threadIdx.x == 0) {
        float a = 0.f, b2 = 0.f;
        for (int i = 0; i < 4; i++) { a += sw[i]; b2 += sw2[i]; }
        sw[0] = a; sw2[0] = b2;
    }
    __syncthreads();
    float mean = sw[0] / DM;
    float var  = sw2[0] / DM - mean * mean;
    float rstd = rsqrtf(var + LN_EPS);
    for (int i = threadIdx.x; i < DM; i += 256) {
        float v = (r[i] - mean) * rstd;
        out[(size_t)row * DM + i] = gamma[i] * v + beta[i];
    }
}

extern "C" void kernel_launch(void* const* d_in, const int* in_sizes, int n_in,
                              void* d_out, int out_size, void* d_ws, size_t ws_size,
                              hipStream_t stream)
{
    const float* x = (const float*)d_in[0];

    float* ws  = (float*)d_ws;
    float* xz  = ws;                                  // B*L*2*DI = 8,388,608 f
    float* xc  = xz  + (size_t)B_ * L_ * 2 * DI;      // B*L*DI   = 4,194,304 f
    float* dbl = xc  + (size_t)B_ * L_ * DI;          // B*L*GG   =   196,608 f
    float* dt  = dbl + (size_t)B_ * L_ * GG;          // B*L*DI   = 4,194,304 f (becomes ys)
    float* yo  = dt  + (size_t)B_ * L_ * DI;          // B*L*DM   = 2,097,152 f
    float* Pb  = yo  + (size_t)B_ * L_ * DM;          // 2,097,152 f
    float* Hb  = Pb  + (size_t)B_ * DI * NC * DS;     // 2,097,152 f
    float* endf = Hb + (size_t)B_ * DI * NC * DS;
    const size_t need_base = (size_t)(endf - ws) * 4;
    bf16* wbf   = (bf16*)endf;                        // 4M bf16 =  8 MB (max weight)
    bf16* actbf = wbf + (size_t)4 * 1024 * 1024;      // 8M bf16 = 16 MB (max activation)
    const size_t need_mfma = need_base + (4 + 8) * (size_t)1024 * 1024 * 2;
    const int use_chunked = (ws_size >= need_base);
    const int use_mfma    = (ws_size >= need_mfma);

    dim3 blk(16, 16);
    const int M = B_ * L_;

    for (int dir = 0; dir < 2; dir++) {
        const float* in_proj   = (const float*)d_in[1 + dir * 9 + 0];
        const float* conv_w    = (const float*)d_in[1 + dir * 9 + 1];
        const float* conv_b    = (const float*)d_in[1 + dir * 9 + 2];
        const float* x_proj    = (const float*)d_in[1 + dir * 9 + 3];
        const float* dt_proj_w = (const float*)d_in[1 + dir * 9 + 4];
        const float* dt_proj_b = (const float*)d_in[1 + dir * 9 + 5];
        const float* A_log     = (const float*)d_in[1 + dir * 9 + 6];
        const float* Dp        = (const float*)d_in[1 + dir * 9 + 7];
        const float* out_proj  = (const float*)d_in[1 + dir * 9 + 8];

        // GEMM1: xz = x(flip?) @ in_proj^T            M x 4096, K=1024
        if (use_mfma) {
            cast_kernel<<<(2 * DI * DM / 4) / 256, 256, 0, stream>>>(in_proj, wbf, 2 * DI * DM / 4);
            cast_flip_kernel<<<(M * DM / 4) / 256, 256, 0, stream>>>(x, actbf, dir);
            dim3 g1(2 * DI / 128, M / 128);
            gemm_mfma<128, 128, 0><<<g1, 256, 0, stream>>>(
                actbf, DM, wbf, DM, xz, 2 * DI, DM, 0, nullptr);
        } else {
            dim3 g1((2 * DI) / 64, M / 64);
            gemm_bt<0><<<g1, blk, 0, stream>>>(
                x, DM, in_proj, DM, xz, 2 * DI, M, 2 * DI, DM, dir, 0, nullptr);
        }

        // conv + silu (+ silu(z) in place)
        conv_silu_kernel<<<(B_ * L_ * DI) / 256, 256, 0, stream>>>(xz, conv_w, conv_b, xc);

        // GEMM2: dbl = xc @ x_proj^T                  M x 96, K=2048
        if (use_mfma) {
            cast_kernel<<<(M * DI / 4) / 256, 256, 0, stream>>>(xc, actbf, M * DI / 4);
            cast_kernel<<<(GG * DI / 4 + 255) / 256, 256, 0, stream>>>(x_proj, wbf, GG * DI / 4);
            hipMemsetAsync(dbl, 0, (size_t)M * GG * sizeof(float), stream);
            dim3 g2(1, M / 128, 8);
            gemm2_mfma<8><<<g2, 256, 0, stream>>>(actbf, wbf, dbl, DI);
        } else {
            dim3 g2((GG + 63) / 64, M / 64);
            gemm_bt<0><<<g2, blk, 0, stream>>>(
                xc, DI, x_proj, DI, dbl, GG, M, GG, DI, 0, 0, nullptr);
        }

        // GEMM3: dt = softplus(dbl[:, :64] @ dt_proj_w^T + b)   M x 2048, K=64
        if (use_mfma) {
            cast_kernel<<<(M * GG / 4) / 256, 256, 0, stream>>>(dbl, actbf, M * GG / 4);
            cast_kernel<<<(DI * RK / 4 + 255) / 256, 256, 0, stream>>>(dt_proj_w, wbf, DI * RK / 4);
            dim3 g3(DI / 128, M / 128);
            gemm_mfma<128, 128, 1><<<g3, 256, 0, stream>>>(
                actbf, GG, wbf, RK, dt, DI, RK, 0, dt_proj_b);
        } else {
            dim3 g3(DI / 64, M / 64);
            gemm_bt<1><<<g3, blk, 0, stream>>>(
                dbl, GG, dt_proj_w, RK, dt, DI, M, DI, RK, 0, 0, dt_proj_b);
        }

        // selective scan + D-skip + z-gating (ys written into dt buffer)
        if (use_chunked) {
            scan_phaseA<<<(B_ * DI * NC * DS) / 256, 256, 0, stream>>>(
                dbl, xc, dt, A_log, Pb, Hb);
            scan_phaseB<<<(B_ * DI * DS) / 256, 256, 0, stream>>>(Pb, Hb);
            scan_phaseC<<<(B_ * (DI / 4) * NC * 64) / 256, 256, 0, stream>>>(
                dbl, xc, dt, xz, A_log, Dp, Hb);
        } else {
            scan_kernel<<<256, 256, 0, stream>>>(dbl, xc, dt, xz, A_log, Dp);
        }

        // GEMM4: yo (+)= ys @ out_proj^T              M x 1024, K=2048
        if (use_mfma) {
            cast_kernel<<<(DM * DI / 4) / 256, 256, 0, stream>>>(out_proj, wbf, DM * DI / 4);
            cast_kernel<<<(M * DI / 4) / 256, 256, 0, stream>>>(dt, actbf, M * DI / 4);
            dim3 g4(DM / 64, M / 128);
            if (dir == 0)
                gemm_mfma<128, 64, 0><<<g4, 256, 0, stream>>>(
                    actbf, DI, wbf, DI, yo, DM, DI, 0, nullptr);
            else
                gemm_mfma<128, 64, 2><<<g4, 256, 0, stream>>>(
                    actbf, DI, wbf, DI, yo, DM, DI, 1, nullptr);
        } else {
            dim3 g4(DM / 64, M / 64);
            if (dir == 0)
                gemm_bt<0><<<g4, blk, 0, stream>>>(
                    dt, DI, out_proj, DI, yo, DM, M, DM, DI, 0, 0, nullptr);
            else
                gemm_bt<2><<<g4, blk, 0, stream>>>(
                    dt, DI, out_proj, DI, yo, DM, M, DM, DI, 0, 1, nullptr);
        }
    }

    ln_kernel<<<B_ * L_, 256, 0, stream>>>(
        yo, (const float*)d_in[19], (const float*)d_in[20], (float*)d_out);
}

// Round 8
// 546.184 us; speedup vs baseline: 7.5693x; 1.3407x over previous
//
#include <hip/hip_runtime.h>
#include <hip/hip_bf16.h>
#include <math.h>

#define B_  2
#define L_  1024
#define DM  1024
#define DI  2048
#define DS  16
#define DC  4
#define RK  64
#define GG  96      // RK + 2*DS
#define NC  32      // scan chunks
#define CL  32      // L_/NC
#define LN_EPS 1e-5f

using bf16 = __hip_bfloat16;
typedef __attribute__((ext_vector_type(8))) short short8;
typedef __attribute__((ext_vector_type(4))) float f32x4;

__device__ __forceinline__ unsigned short f2bf(float f) {
    union { float f; unsigned u; } x; x.f = f;
    unsigned r = x.u + 0x7fffu + ((x.u >> 16) & 1u);   // round-to-nearest-even
    return (unsigned short)(r >> 16);
}

// ---------------- fp32 fallback / small GEMM ----------------
template<int EPI>
__global__ __launch_bounds__(256)
void gemm_bt(const float* __restrict__ A, int lda,
             const float* __restrict__ W, int ldw,
             float* __restrict__ C, int ldc,
             int M, int N, int K, int flipA, int flipC,
             const float* __restrict__ bias)
{
    __shared__ float As[16][65];
    __shared__ float Ws[16][65];
    const int m0 = blockIdx.y * 64;
    const int n0 = blockIdx.x * 64;
    const int tx = threadIdx.x, ty = threadIdx.y;
    const int tid = ty * 16 + tx;
    float acc[4][4] = {};

    for (int k0 = 0; k0 < K; k0 += 16) {
        for (int e = tid; e < 1024; e += 256) {
            int mm = e >> 4, kk = e & 15;
            int gm = m0 + mm, gk = k0 + kk;
            float va = 0.f;
            if (gm < M && gk < K) {
                int pr = gm;
                if (flipA) { int b = gm / L_; int l = gm % L_; pr = b * L_ + (L_ - 1 - l); }
                va = A[(size_t)pr * lda + gk];
            }
            As[kk][mm] = va;
            int gn = n0 + mm;
            float vw = 0.f;
            if (gn < N && gk < K) vw = W[(size_t)gn * ldw + gk];
            Ws[kk][mm] = vw;
        }
        __syncthreads();
        #pragma unroll
        for (int k = 0; k < 16; k++) {
            float a[4], w[4];
            #pragma unroll
            for (int i = 0; i < 4; i++) a[i] = As[k][ty * 4 + i];
            #pragma unroll
            for (int j = 0; j < 4; j++) w[j] = Ws[k][tx * 4 + j];
            #pragma unroll
            for (int i = 0; i < 4; i++)
                #pragma unroll
                for (int j = 0; j < 4; j++) acc[i][j] += a[i] * w[j];
        }
        __syncthreads();
    }

    #pragma unroll
    for (int i = 0; i < 4; i++) {
        int m = m0 + ty * 4 + i;
        if (m >= M) continue;
        int mo = m;
        if (flipC) { int b = m / L_; int l = m % L_; mo = b * L_ + (L_ - 1 - l); }
        #pragma unroll
        for (int j = 0; j < 4; j++) {
            int n = n0 + tx * 4 + j;
            if (n >= N) continue;
            float v = acc[i][j];
            if (EPI == 1) { v += bias[n]; v = (v > 20.f) ? v : log1pf(expf(v)); }
            float* p = &C[(size_t)mo * ldc + n];
            if (EPI == 2) v += *p;
            *p = v;
        }
    }
}

// ---------------- bf16 MFMA GEMM ----------------
// C[M x N] = A[M x Keff](row stride lda) * W[N x Keff]^T(row stride ldw), fp32 out.
// EPI: 0 store, 1 bias+softplus, 2 read-add(+flipC)
template<int BM, int BN, int EPI>
__global__ __launch_bounds__(256)
void gemm_mfma(const bf16* __restrict__ A, int lda,
               const bf16* __restrict__ W, int ldw,
               float* __restrict__ C, int ldc, int K, int flipC,
               const float* __restrict__ bias)
{
    constexpr int WMx = BM / 2, WNx = BN / 2, MT = WMx / 16, NT = WNx / 16;
    __shared__ __align__(16) bf16 As[BM * 32];
    __shared__ __align__(16) bf16 Bs[BN * 32];
    const int tid  = threadIdx.x;
    const int lane = tid & 63;
    const int wave = tid >> 6;
    const int wm = wave >> 1, wn = wave & 1;
    const int r16 = lane & 15, quad = lane >> 4;
    const int m0 = blockIdx.y * BM, n0 = blockIdx.x * BN;
    const int wavebase = (tid & ~63);

    f32x4 acc[MT][NT] = {};

    for (int k0 = 0; k0 < K; k0 += 32) {
        #pragma unroll
        for (int r = 0; r < BM * 4; r += 256) {
            int c = r + tid;
            const bf16* g = A + (size_t)(m0 + (c >> 2)) * lda + k0 + (c & 3) * 8;
            bf16* l = As + (size_t)(r + wavebase) * 8;
            __builtin_amdgcn_global_load_lds(
                (const __attribute__((address_space(1))) void*)g,
                (__attribute__((address_space(3))) void*)l, 16, 0, 0);
        }
        #pragma unroll
        for (int r = 0; r < BN * 4; r += 256) {
            int c = r + tid;
            const bf16* g = W + (size_t)(n0 + (c >> 2)) * ldw + k0 + (c & 3) * 8;
            bf16* l = Bs + (size_t)(r + wavebase) * 8;
            __builtin_amdgcn_global_load_lds(
                (const __attribute__((address_space(1))) void*)g,
                (__attribute__((address_space(3))) void*)l, 16, 0, 0);
        }
        __syncthreads();

        short8 af[MT], bfr[NT];
        #pragma unroll
        for (int i = 0; i < MT; i++)
            af[i] = *(const short8*)&As[(wm * WMx + i * 16 + r16) * 32 + quad * 8];
        #pragma unroll
        for (int j = 0; j < NT; j++)
            bfr[j] = *(const short8*)&Bs[(wn * WNx + j * 16 + r16) * 32 + quad * 8];
        #pragma unroll
        for (int i = 0; i < MT; i++)
            #pragma unroll
            for (int j = 0; j < NT; j++)
                acc[i][j] = __builtin_amdgcn_mfma_f32_16x16x32_bf16(
                    af[i], bfr[j], acc[i][j], 0, 0, 0);
        __syncthreads();
    }

    #pragma unroll
    for (int i = 0; i < MT; i++) {
        #pragma unroll
        for (int r = 0; r < 4; r++) {
            int m = m0 + wm * WMx + i * 16 + quad * 4 + r;
            int mo = m;
            if (flipC) { int b = m / L_; int l = m % L_; mo = b * L_ + (L_ - 1 - l); }
            #pragma unroll
            for (int j = 0; j < NT; j++) {
                int n = n0 + wn * WNx + j * 16 + r16;
                float v = acc[i][j][r];
                if (EPI == 1) {
                    v += bias[n];
                    v = (v > 20.f) ? v : __logf(1.f + __expf(v));
                }
                float* p = &C[(size_t)mo * ldc + n];
                if (EPI == 2) v += *p;
                *p = v;
            }
        }
    }
}

// ---------------- GEMM2 MFMA: M x 96, split-K, atomic accumulate ----------------
template<int SPLITK>
__global__ __launch_bounds__(256)
void gemm2_mfma(const bf16* __restrict__ A, const bf16* __restrict__ W,
                float* __restrict__ C, int K)
{
    constexpr int BM = 128, BN = 96;
    constexpr int WMx = 64, WNx = 48, MT = 4, NT = 3;
    __shared__ __align__(16) bf16 As[BM * 32];
    __shared__ __align__(16) bf16 Bs[BN * 32];
    const int tid  = threadIdx.x;
    const int lane = tid & 63;
    const int wave = tid >> 6;
    const int wm = wave >> 1, wn = wave & 1;
    const int r16 = lane & 15, quad = lane >> 4;
    const int m0 = blockIdx.y * BM;
    const int wavebase = (tid & ~63);
    const int kper = K / SPLITK;
    const int kbeg = blockIdx.z * kper;

    f32x4 acc[MT][NT] = {};

    for (int kk = 0; kk < kper; kk += 32) {
        int k0 = kbeg + kk;
        #pragma unroll
        for (int r = 0; r < BM * 4; r += 256) {
            int c = r + tid;
            const bf16* g = A + (size_t)(m0 + (c >> 2)) * K + k0 + (c & 3) * 8;
            bf16* l = As + (size_t)(r + wavebase) * 8;
            __builtin_amdgcn_global_load_lds(
                (const __attribute__((address_space(1))) void*)g,
                (__attribute__((address_space(3))) void*)l, 16, 0, 0);
        }
        #pragma unroll
        for (int r = 0; r < BN * 4; r += 256) {
            if (r + wavebase < BN * 4) {          // wave-uniform guard (384 = 6 waves)
                int c = r + tid;
                const bf16* g = W + (size_t)(c >> 2) * K + k0 + (c & 3) * 8;
                bf16* l = Bs + (size_t)(r + wavebase) * 8;
                __builtin_amdgcn_global_load_lds(
                    (const __attribute__((address_space(1))) void*)g,
                    (__attribute__((address_space(3))) void*)l, 16, 0, 0);
            }
        }
        __syncthreads();

        short8 af[MT], bfr[NT];
        #pragma unroll
        for (int i = 0; i < MT; i++)
            af[i] = *(const short8*)&As[(wm * WMx + i * 16 + r16) * 32 + quad * 8];
        #pragma unroll
        for (int j = 0; j < NT; j++)
            bfr[j] = *(const short8*)&Bs[(wn * WNx + j * 16 + r16) * 32 + quad * 8];
        #pragma unroll
        for (int i = 0; i < MT; i++)
            #pragma unroll
            for (int j = 0; j < NT; j++)
                acc[i][j] = __builtin_amdgcn_mfma_f32_16x16x32_bf16(
                    af[i], bfr[j], acc[i][j], 0, 0, 0);
        __syncthreads();
    }

    #pragma unroll
    for (int i = 0; i < MT; i++) {
        #pragma unroll
        for (int r = 0; r < 4; r++) {
            int m = m0 + wm * WMx + i * 16 + quad * 4 + r;
            #pragma unroll
            for (int j = 0; j < NT; j++) {
                int n = wn * WNx + j * 16 + r16;
                atomicAdd(&C[(size_t)m * GG + n], acc[i][j][r]);
            }
        }
    }
}

// ---------------- casts ----------------
__global__ __launch_bounds__(256)
void cast_kernel(const float* __restrict__ in, bf16* __restrict__ out, int n4)
{
    int i = blockIdx.x * 256 + threadIdx.x;
    if (i >= n4) return;
    float4 v = ((const float4*)in)[i];
    ushort4 o; o.x = f2bf(v.x); o.y = f2bf(v.y); o.z = f2bf(v.z); o.w = f2bf(v.w);
    ((ushort4*)out)[i] = o;
}

__global__ __launch_bounds__(256)
void cast_flip_kernel(const float* __restrict__ in, bf16* __restrict__ out, int flip)
{
    int i = blockIdx.x * 256 + threadIdx.x;        // over B*L*DM/4
    int k4 = i & (DM / 4 - 1); int m = i / (DM / 4);
    int b = m / L_, l = m % L_;
    int src = flip ? (b * L_ + (L_ - 1 - l)) : m;
    float4 v = ((const float4*)(in + (size_t)src * DM))[k4];
    ushort4 o; o.x = f2bf(v.x); o.y = f2bf(v.y); o.z = f2bf(v.z); o.w = f2bf(v.w);
    ((ushort4*)(out + (size_t)m * DM))[k4] = o;
}

// gated cast for GEMM4: out_bf16 = (ys_raw + xc*D) * silu(z)
__global__ __launch_bounds__(256)
void gate_cast_kernel(const float* __restrict__ ys, const float* __restrict__ xc,
                      const float* __restrict__ xz, const float* __restrict__ Dp,
                      bf16* __restrict__ out)
{
    int i = blockIdx.x * 256 + threadIdx.x;        // over M*DI/4
    int d4 = i & (DI / 4 - 1); int m = i >> 9;
    float4 y = ((const float4*)ys)[i];
    float4 x = ((const float4*)xc)[i];
    float4 z = *(const float4*)(xz + (size_t)m * (2 * DI) + DI + 4 * d4);
    float4 D = ((const float4*)Dp)[d4];
    float v0 = (y.x + x.x * D.x) * (z.x / (1.f + __expf(-z.x)));
    float v1 = (y.y + x.y * D.y) * (z.y / (1.f + __expf(-z.y)));
    float v2 = (y.z + x.z * D.z) * (z.z / (1.f + __expf(-z.z)));
    float v3 = (y.w + x.w * D.w) * (z.w / (1.f + __expf(-z.w)));
    ushort4 o; o.x = f2bf(v0); o.y = f2bf(v1); o.z = f2bf(v2); o.w = f2bf(v3);
    ((ushort4*)out)[i] = o;
}

// ---------------- conv + silu ----------------
__global__ __launch_bounds__(256)
void conv_silu_kernel(const float* __restrict__ xz, const float* __restrict__ conv_w,
                      const float* __restrict__ conv_b, float* __restrict__ xc)
{
    int idx = blockIdx.x * 256 + threadIdx.x;
    int d = idx % DI; int bl = idx / DI; int l = bl % L_; int b = bl / L_;
    float acc = conv_b[d];
    #pragma unroll
    for (int k = 0; k < DC; k++) {
        int ls = l + k - (DC - 1);
        if (ls >= 0)
            acc += xz[(size_t)(b * L_ + ls) * (2 * DI) + d] * conv_w[d * DC + k];
    }
    xc[idx] = acc / (1.f + __expf(-acc));
}

// ---------------- chunk-parallel selective scan, d-on-lanes layout ----------------
// wave = (b, dblk of 64 d, chunk c); lane = d offset. Each lane holds all 16 n-states.
// P/H layout: [wave][n][lane] i.e. idx = wv*1024 + n*64 + lane.
__global__ __launch_bounds__(256)
void scan_phaseA(const float* __restrict__ dbl, const float* __restrict__ xc,
                 const float* __restrict__ dts, const float* __restrict__ A_log,
                 float* __restrict__ Pbuf, float* __restrict__ Hbuf)
{
    int t = blockIdx.x * 256 + threadIdx.x;
    int lane = t & 63, wv = t >> 6;
    int c = wv & (NC - 1);
    int bd = wv >> 5;                  // b*32 + dblk
    int d = (bd & 31) * 64 + lane;
    int b = bd >> 5;

    float Aval[16];
    {
        const float4* pa = (const float4*)(A_log + d * DS);
        #pragma unroll
        for (int q = 0; q < 4; q++) {
            float4 v = pa[q];
            Aval[4*q+0] = -__expf(v.x); Aval[4*q+1] = -__expf(v.y);
            Aval[4*q+2] = -__expf(v.z); Aval[4*q+3] = -__expf(v.w);
        }
    }
    float P[16], H[16];
    #pragma unroll
    for (int n = 0; n < 16; n++) { P[n] = 1.f; H[n] = 0.f; }

    int l0 = c * CL;
    const float* pdt = dts + (size_t)(b * L_ + l0) * DI + d;
    const float* pxc = xc  + (size_t)(b * L_ + l0) * DI + d;
    const float* pB  = dbl + (size_t)(b * L_ + l0) * GG + RK;

    for (int i = 0; i < CL; i++) {
        float dt = *pdt, x = *pxc;
        float dtx = dt * x;
        float Bn[16];
        #pragma unroll
        for (int q = 0; q < 4; q++) {
            float4 v = ((const float4*)pB)[q];
            Bn[4*q+0] = v.x; Bn[4*q+1] = v.y; Bn[4*q+2] = v.z; Bn[4*q+3] = v.w;
        }
        #pragma unroll
        for (int n = 0; n < 16; n++) {
            float dA = __expf(dt * Aval[n]);
            P[n] *= dA;
            H[n] = dA * H[n] + dtx * Bn[n];
        }
        pdt += DI; pxc += DI; pB += GG;
    }
    size_t obase = (size_t)wv * 1024 + lane;
    #pragma unroll
    for (int n = 0; n < 16; n++) { Pbuf[obase + n * 64] = P[n]; Hbuf[obase + n * 64] = H[n]; }
}

// thread per (b, dblk, n, lane): sequential combine over NC chunks (in place).
__global__ __launch_bounds__(256)
void scan_phaseB(const float* __restrict__ Pbuf, float* __restrict__ Hbuf)
{
    int t = blockIdx.x * 256 + threadIdx.x;   // 64*16*64 = 65536 threads
    int lane = t & 63; int n = (t >> 6) & 15; int bd = t >> 10;
    size_t base = (size_t)bd * NC * 1024 + n * 64 + lane;
    float run = 0.f;
    for (int c = 0; c < NC; c++) {
        size_t idx = base + (size_t)c * 1024;
        float P  = Pbuf[idx];
        float Hl = Hbuf[idx];
        Hbuf[idx] = run;
        run = Hl + P * run;
    }
}

// Re-runs scan from chunk-entry state; writes RAW y (= sum_n h*C) coalesced.
__global__ __launch_bounds__(256)
void scan_phaseC(const float* __restrict__ dbl, const float* __restrict__ xc,
                 float* __restrict__ dtys, const float* __restrict__ A_log,
                 const float* __restrict__ Hbuf)
{
    int t = blockIdx.x * 256 + threadIdx.x;
    int lane = t & 63, wv = t >> 6;
    int c = wv & (NC - 1);
    int bd = wv >> 5;
    int d = (bd & 31) * 64 + lane;
    int b = bd >> 5;

    float Aval[16];
    {
        const float4* pa = (const float4*)(A_log + d * DS);
        #pragma unroll
        for (int q = 0; q < 4; q++) {
            float4 v = pa[q];
            Aval[4*q+0] = -__expf(v.x); Aval[4*q+1] = -__expf(v.y);
            Aval[4*q+2] = -__expf(v.z); Aval[4*q+3] = -__expf(v.w);
        }
    }
    float h[16];
    size_t hbase = (size_t)wv * 1024 + lane;
    #pragma unroll
    for (int n = 0; n < 16; n++) h[n] = Hbuf[hbase + n * 64];

    int l0 = c * CL;
    const float* pdt = dtys + (size_t)(b * L_ + l0) * DI + d;
    float*       pw  = dtys + (size_t)(b * L_ + l0) * DI + d;
    const float* pxc = xc   + (size_t)(b * L_ + l0) * DI + d;
    const float* pB  = dbl  + (size_t)(b * L_ + l0) * GG + RK;

    for (int i = 0; i < CL; i++) {
        float dt = *pdt, x = *pxc;
        float dtx = dt * x;
        float Bn[16], Cn[16];
        #pragma unroll
        for (int q = 0; q < 4; q++) {
            float4 v = ((const float4*)pB)[q];
            Bn[4*q+0] = v.x; Bn[4*q+1] = v.y; Bn[4*q+2] = v.z; Bn[4*q+3] = v.w;
            float4 w = ((const float4*)pB)[q + 4];
            Cn[4*q+0] = w.x; Cn[4*q+1] = w.y; Cn[4*q+2] = w.z; Cn[4*q+3] = w.w;
        }
        float y = 0.f;
        #pragma unroll
        for (int n = 0; n < 16; n++) {
            float dA = __expf(dt * Aval[n]);
            h[n] = dA * h[n] + dtx * Bn[n];
            y += h[n] * Cn[n];
        }
        *pw = y;
        pdt += DI; pw += DI; pxc += DI; pB += GG;
    }
}

// Fallback single-pass scan (writes fully gated y; z raw in xz)
__global__ __launch_bounds__(256)
void scan_kernel(const float* __restrict__ dbl, const float* __restrict__ xc,
                 float* __restrict__ dtys, const float* __restrict__ xz,
                 const float* __restrict__ A_log, const float* __restrict__ Dp)
{
    int t = blockIdx.x * 256 + threadIdx.x;
    int lane = t & 63; int w = t >> 6;
    int n = lane & 15; int dsub = lane >> 4;
    int b = w / (DI / 4); int dgrp = w % (DI / 4);
    int d = dgrp * 4 + dsub;

    float Aval = -__expf(A_log[d * DS + n]);
    float Dval = Dp[d];
    float h = 0.f;
    const float* dblb = dbl + (size_t)(b * L_) * GG;

    for (int l = 0; l < L_; l++) {
        size_t ro = (size_t)(b * L_ + l);
        float dt = dtys[ro * DI + d];
        float x  = xc[ro * DI + d];
        float Bn = dblb[l * GG + RK + n];
        float Cn = dblb[l * GG + RK + DS + n];
        float dA = __expf(dt * Aval);
        h = dA * h + dt * x * Bn;
        float c = h * Cn;
        c += __shfl_xor(c, 8, 16);
        c += __shfl_xor(c, 4, 16);
        c += __shfl_xor(c, 2, 16);
        c += __shfl_xor(c, 1, 16);
        if (n == 0) {
            float z = xz[ro * (2 * DI) + DI + d];
            float sz = z / (1.f + __expf(-z));
            dtys[ro * DI + d] = (c + x * Dval) * sz;
        }
    }
}

__global__ __launch_bounds__(256)
void ln_kernel(const float* __restrict__ yo, const float* __restrict__ gamma,
               const float* __restrict__ beta, float* __restrict__ out)
{
    int row = blockIdx.x;
    const float* r = yo + (size_t)row * DM;
    float s = 0.f, s2 = 0.f;
    for (int i = threadIdx.x; i < DM; i += 256) { float v = r[i]; s += v; s2 += v * v; }
    #pragma unroll
    for (int o = 32; o > 0; o >>= 1) { s += __shfl_down(s, o); s2 += __shfl_down(s2, o); }
    __shared__ float sw[4], sw2[4];
    int wid = threadIdx.x >> 6, ln = threadIdx.x & 63;
    if (ln == 0) { sw[wid] = s; sw2[wid] = s2; }
    __syncthreads();
    if (threadIdx.x == 0) {
        float a = 0.f, b2 = 0.f;
        for (int i = 0; i < 4; i++) { a += sw[i]; b2 += sw2[i]; }
        sw[0] = a; sw2[0] = b2;
    }
    __syncthreads();
    float mean = sw[0] / DM;
    float var  = sw2[0] / DM - mean * mean;
    float rstd = rsqrtf(var + LN_EPS);
    for (int i = threadIdx.x; i < DM; i += 256) {
        float v = (r[i] - mean) * rstd;
        out[(size_t)row * DM + i] = gamma[i] * v + beta[i];
    }
}

extern "C" void kernel_launch(void* const* d_in, const int* in_sizes, int n_in,
                              void* d_out, int out_size, void* d_ws, size_t ws_size,
                              hipStream_t stream)
{
    const float* x = (const float*)d_in[0];

    float* ws  = (float*)d_ws;
    float* xz  = ws;                                  // B*L*2*DI = 8,388,608 f
    float* xc  = xz  + (size_t)B_ * L_ * 2 * DI;      // B*L*DI   = 4,194,304 f
    float* dbl = xc  + (size_t)B_ * L_ * DI;          // B*L*GG   =   196,608 f
    float* dt  = dbl + (size_t)B_ * L_ * GG;          // B*L*DI   = 4,194,304 f (becomes ys)
    float* yo  = dt  + (size_t)B_ * L_ * DI;          // B*L*DM   = 2,097,152 f
    float* Pb  = yo  + (size_t)B_ * L_ * DM;          // 2,097,152 f
    float* Hb  = Pb  + (size_t)B_ * DI * NC * DS;     // 2,097,152 f
    float* endf = Hb + (size_t)B_ * DI * NC * DS;
    const size_t need_base = (size_t)(endf - ws) * 4;
    bf16* wbf   = (bf16*)endf;                        // 4M bf16 =  8 MB (max weight)
    bf16* actbf = wbf + (size_t)4 * 1024 * 1024;      // 8M bf16 = 16 MB (max activation)
    const size_t need_mfma = need_base + (4 + 8) * (size_t)1024 * 1024 * 2;
    const int use_chunked = (ws_size >= need_base);
    const int use_mfma    = (ws_size >= need_mfma);

    dim3 blk(16, 16);
    const int M = B_ * L_;

    for (int dir = 0; dir < 2; dir++) {
        const float* in_proj   = (const float*)d_in[1 + dir * 9 + 0];
        const float* conv_w    = (const float*)d_in[1 + dir * 9 + 1];
        const float* conv_b    = (const float*)d_in[1 + dir * 9 + 2];
        const float* x_proj    = (const float*)d_in[1 + dir * 9 + 3];
        const float* dt_proj_w = (const float*)d_in[1 + dir * 9 + 4];
        const float* dt_proj_b = (const float*)d_in[1 + dir * 9 + 5];
        const float* A_log     = (const float*)d_in[1 + dir * 9 + 6];
        const float* Dp        = (const float*)d_in[1 + dir * 9 + 7];
        const float* out_proj  = (const float*)d_in[1 + dir * 9 + 8];

        // GEMM1: xz = x(flip?) @ in_proj^T            M x 4096, K=1024
        if (use_mfma) {
            cast_kernel<<<(2 * DI * DM / 4) / 256, 256, 0, stream>>>(in_proj, wbf, 2 * DI * DM / 4);
            cast_flip_kernel<<<(M * DM / 4) / 256, 256, 0, stream>>>(x, actbf, dir);
            dim3 g1(2 * DI / 128, M / 128);
            gemm_mfma<128, 128, 0><<<g1, 256, 0, stream>>>(
                actbf, DM, wbf, DM, xz, 2 * DI, DM, 0, nullptr);
        } else {
            dim3 g1((2 * DI) / 64, M / 64);
            gemm_bt<0><<<g1, blk, 0, stream>>>(
                x, DM, in_proj, DM, xz, 2 * DI, M, 2 * DI, DM, dir, 0, nullptr);
        }

        // conv + silu
        conv_silu_kernel<<<(B_ * L_ * DI) / 256, 256, 0, stream>>>(xz, conv_w, conv_b, xc);

        // GEMM2: dbl = xc @ x_proj^T                  M x 96, K=2048
        if (use_mfma) {
            cast_kernel<<<(M * DI / 4) / 256, 256, 0, stream>>>(xc, actbf, M * DI / 4);
            cast_kernel<<<(GG * DI / 4 + 255) / 256, 256, 0, stream>>>(x_proj, wbf, GG * DI / 4);
            hipMemsetAsync(dbl, 0, (size_t)M * GG * sizeof(float), stream);
            dim3 g2(1, M / 128, 8);
            gemm2_mfma<8><<<g2, 256, 0, stream>>>(actbf, wbf, dbl, DI);
        } else {
            dim3 g2((GG + 63) / 64, M / 64);
            gemm_bt<0><<<g2, blk, 0, stream>>>(
                xc, DI, x_proj, DI, dbl, GG, M, GG, DI, 0, 0, nullptr);
        }

        // GEMM3: dt = softplus(dbl[:, :64] @ dt_proj_w^T + b)   M x 2048, K=64
        if (use_mfma) {
            cast_kernel<<<(M * GG / 4) / 256, 256, 0, stream>>>(dbl, actbf, M * GG / 4);
            cast_kernel<<<(DI * RK / 4 + 255) / 256, 256, 0, stream>>>(dt_proj_w, wbf, DI * RK / 4);
            dim3 g3(DI / 128, M / 128);
            gemm_mfma<128, 128, 1><<<g3, 256, 0, stream>>>(
                actbf, GG, wbf, RK, dt, DI, RK, 0, dt_proj_b);
        } else {
            dim3 g3(DI / 64, M / 64);
            gemm_bt<1><<<g3, blk, 0, stream>>>(
                dbl, GG, dt_proj_w, RK, dt, DI, M, DI, RK, 0, 0, dt_proj_b);
        }

        // selective scan (raw y) then gating fused into GEMM4 cast
        if (use_chunked) {
            scan_phaseA<<<512, 256, 0, stream>>>(dbl, xc, dt, A_log, Pb, Hb);
            scan_phaseB<<<256, 256, 0, stream>>>(Pb, Hb);
            scan_phaseC<<<512, 256, 0, stream>>>(dbl, xc, dt, A_log, Hb);
        } else {
            scan_kernel<<<256, 256, 0, stream>>>(dbl, xc, dt, xz, A_log, Dp);
        }

        // GEMM4: yo (+)= ys @ out_proj^T              M x 1024, K=2048
        if (use_mfma) {
            cast_kernel<<<(DM * DI / 4) / 256, 256, 0, stream>>>(out_proj, wbf, DM * DI / 4);
            if (use_chunked)
                gate_cast_kernel<<<(M * DI / 4) / 256, 256, 0, stream>>>(dt, xc, xz, Dp, actbf);
            else
                cast_kernel<<<(M * DI / 4) / 256, 256, 0, stream>>>(dt, actbf, M * DI / 4);
            dim3 g4(DM / 64, M / 128);
            if (dir == 0)
                gemm_mfma<128, 64, 0><<<g4, 256, 0, stream>>>(
                    actbf, DI, wbf, DI, yo, DM, DI, 0, nullptr);
            else
                gemm_mfma<128, 64, 2><<<g4, 256, 0, stream>>>(
                    actbf, DI, wbf, DI, yo, DM, DI, 1, nullptr);
        } else {
            // fp32 path: need gated ys in dt; fallback scan already gated it
            dim3 g4(DM / 64, M / 64);
            if (dir == 0)
                gemm_bt<0><<<g4, blk, 0, stream>>>(
                    dt, DI, out_proj, DI, yo, DM, M, DM, DI, 0, 0, nullptr);
            else
                gemm_bt<2><<<g4, blk, 0, stream>>>(
                    dt, DI, out_proj, DI, yo, DM, M, DM, DI, 0, 1, nullptr);
        }
    }

    ln_kernel<<<B_ * L_, 256, 0, stream>>>(
        yo, (const float*)d_in[19], (const float*)d_in[20], (float*)d_out);
}

// Round 9
// 429.445 us; speedup vs baseline: 9.6268x; 1.2718x over previous
//
#include <hip/hip_runtime.h>
#include <hip/hip_bf16.h>
#include <math.h>

#define B_  2
#define L_  1024
#define DM  1024
#define DI  2048
#define DS  16
#define DC  4
#define RK  64
#define GG  96      // RK + 2*DS
#define NC  32      // scan chunks
#define CL  32      // L_/NC
#define LN_EPS 1e-5f
#define MM  (B_ * L_)   // 2048 rows

using bf16 = __hip_bfloat16;
typedef __attribute__((ext_vector_type(8))) short short8;
typedef __attribute__((ext_vector_type(4))) float f32x4;

__device__ __forceinline__ unsigned short f2bf(float f) {
    union { float f; unsigned u; } x; x.f = f;
    unsigned r = x.u + 0x7fffu + ((x.u >> 16) & 1u);   // RNE
    return (unsigned short)(r >> 16);
}

// ================= batched bf16 MFMA GEMM (dir = blockIdx.z) =================
// C[M x N] = A[M x Keff](lda) * W[N x Keff]^T(ldw); per-dir strides sA/sW/sC.
// EPI: 0 store, 1 bias+softplus. flipDir1: flip C rows for dir 1.
template<int BM, int BN, int EPI>
__global__ __launch_bounds__(256)
void gemm_mfma_b(const bf16* __restrict__ A, int lda, size_t sA,
                 const bf16* __restrict__ W, int ldw, size_t sW,
                 float* __restrict__ C, int ldc, size_t sC,
                 int K, int flipDir1,
                 const float* __restrict__ b0, const float* __restrict__ b1)
{
    constexpr int WMx = BM / 2, WNx = BN / 2, MT = WMx / 16, NT = WNx / 16;
    __shared__ __align__(16) bf16 As[BM * 32];
    __shared__ __align__(16) bf16 Bs[BN * 32];
    const int dir = blockIdx.z;
    A += (size_t)dir * sA; W += (size_t)dir * sW; C += (size_t)dir * sC;
    const int flipC = flipDir1 && dir;
    const float* bias = dir ? b1 : b0;

    const int tid  = threadIdx.x;
    const int lane = tid & 63;
    const int wave = tid >> 6;
    const int wm = wave >> 1, wn = wave & 1;
    const int r16 = lane & 15, quad = lane >> 4;
    const int m0 = blockIdx.y * BM, n0 = blockIdx.x * BN;
    const int wavebase = (tid & ~63);

    f32x4 acc[MT][NT] = {};

    for (int k0 = 0; k0 < K; k0 += 32) {
        #pragma unroll
        for (int r = 0; r < BM * 4; r += 256) {
            int c = r + tid;
            const bf16* g = A + (size_t)(m0 + (c >> 2)) * lda + k0 + (c & 3) * 8;
            bf16* l = As + (size_t)(r + wavebase) * 8;
            __builtin_amdgcn_global_load_lds(
                (const __attribute__((address_space(1))) void*)g,
                (__attribute__((address_space(3))) void*)l, 16, 0, 0);
        }
        #pragma unroll
        for (int r = 0; r < BN * 4; r += 256) {
            int c = r + tid;
            const bf16* g = W + (size_t)(n0 + (c >> 2)) * ldw + k0 + (c & 3) * 8;
            bf16* l = Bs + (size_t)(r + wavebase) * 8;
            __builtin_amdgcn_global_load_lds(
                (const __attribute__((address_space(1))) void*)g,
                (__attribute__((address_space(3))) void*)l, 16, 0, 0);
        }
        __syncthreads();

        short8 af[MT], bfr[NT];
        #pragma unroll
        for (int i = 0; i < MT; i++)
            af[i] = *(const short8*)&As[(wm * WMx + i * 16 + r16) * 32 + quad * 8];
        #pragma unroll
        for (int j = 0; j < NT; j++)
            bfr[j] = *(const short8*)&Bs[(wn * WNx + j * 16 + r16) * 32 + quad * 8];
        #pragma unroll
        for (int i = 0; i < MT; i++)
            #pragma unroll
            for (int j = 0; j < NT; j++)
                acc[i][j] = __builtin_amdgcn_mfma_f32_16x16x32_bf16(
                    af[i], bfr[j], acc[i][j], 0, 0, 0);
        __syncthreads();
    }

    #pragma unroll
    for (int i = 0; i < MT; i++) {
        #pragma unroll
        for (int r = 0; r < 4; r++) {
            int m = m0 + wm * WMx + i * 16 + quad * 4 + r;
            int mo = m;
            if (flipC) { int b = m / L_; int l = m % L_; mo = b * L_ + (L_ - 1 - l); }
            #pragma unroll
            for (int j = 0; j < NT; j++) {
                int n = n0 + wn * WNx + j * 16 + r16;
                float v = acc[i][j][r];
                if (EPI == 1) {
                    v += bias[n];
                    v = (v > 20.f) ? v : __logf(1.f + __expf(v));
                }
                C[(size_t)mo * ldc + n] = v;
            }
        }
    }
}

// ============ batched GEMM2: M x 96, split-K, atomic accumulate ============
// blockIdx.z = dir*SPLITK + kz. C (both dirs) must be zeroed.
template<int SPLITK>
__global__ __launch_bounds__(256)
void gemm2_mfma_b(const bf16* __restrict__ A, const bf16* __restrict__ W,
                  float* __restrict__ C, int K)
{
    constexpr int BM = 128, BN = 96;
    constexpr int WMx = 64, WNx = 48, MT = 4, NT = 3;
    __shared__ __align__(16) bf16 As[BM * 32];
    __shared__ __align__(16) bf16 Bs[BN * 32];
    const int z = blockIdx.z;
    const int dir = z / SPLITK, kz = z % SPLITK;
    A += (size_t)dir * MM * DI;
    W += (size_t)dir * GG * DI;
    C += (size_t)dir * MM * GG;

    const int tid  = threadIdx.x;
    const int lane = tid & 63;
    const int wave = tid >> 6;
    const int wm = wave >> 1, wn = wave & 1;
    const int r16 = lane & 15, quad = lane >> 4;
    const int m0 = blockIdx.y * BM;
    const int wavebase = (tid & ~63);
    const int kper = K / SPLITK;
    const int kbeg = kz * kper;

    f32x4 acc[MT][NT] = {};

    for (int kk = 0; kk < kper; kk += 32) {
        int k0 = kbeg + kk;
        #pragma unroll
        for (int r = 0; r < BM * 4; r += 256) {
            int c = r + tid;
            const bf16* g = A + (size_t)(m0 + (c >> 2)) * K + k0 + (c & 3) * 8;
            bf16* l = As + (size_t)(r + wavebase) * 8;
            __builtin_amdgcn_global_load_lds(
                (const __attribute__((address_space(1))) void*)g,
                (__attribute__((address_space(3))) void*)l, 16, 0, 0);
        }
        #pragma unroll
        for (int r = 0; r < BN * 4; r += 256) {
            if (r + wavebase < BN * 4) {          // wave-uniform guard (384 = 6 waves)
                int c = r + tid;
                const bf16* g = W + (size_t)(c >> 2) * K + k0 + (c & 3) * 8;
                bf16* l = Bs + (size_t)(r + wavebase) * 8;
                __builtin_amdgcn_global_load_lds(
                    (const __attribute__((address_space(1))) void*)g,
                    (__attribute__((address_space(3))) void*)l, 16, 0, 0);
            }
        }
        __syncthreads();

        short8 af[MT], bfr[NT];
        #pragma unroll
        for (int i = 0; i < MT; i++)
            af[i] = *(const short8*)&As[(wm * WMx + i * 16 + r16) * 32 + quad * 8];
        #pragma unroll
        for (int j = 0; j < NT; j++)
            bfr[j] = *(const short8*)&Bs[(wn * WNx + j * 16 + r16) * 32 + quad * 8];
        #pragma unroll
        for (int i = 0; i < MT; i++)
            #pragma unroll
            for (int j = 0; j < NT; j++)
                acc[i][j] = __builtin_amdgcn_mfma_f32_16x16x32_bf16(
                    af[i], bfr[j], acc[i][j], 0, 0, 0);
        __syncthreads();
    }

    #pragma unroll
    for (int i = 0; i < MT; i++) {
        #pragma unroll
        for (int r = 0; r < 4; r++) {
            int m = m0 + wm * WMx + i * 16 + quad * 4 + r;
            #pragma unroll
            for (int j = 0; j < NT; j++) {
                int n = wn * WNx + j * 16 + r16;
                atomicAdd(&C[(size_t)m * GG + n], acc[i][j][r]);
            }
        }
    }
}

// ================= casts =================
__global__ __launch_bounds__(256)
void cast_kernel(const float* __restrict__ in, bf16* __restrict__ out, int n4)
{
    int i = blockIdx.x * 256 + threadIdx.x;
    if (i >= n4) return;
    float4 v = ((const float4*)in)[i];
    ushort4 o; o.x = f2bf(v.x); o.y = f2bf(v.y); o.z = f2bf(v.z); o.w = f2bf(v.w);
    ((ushort4*)out)[i] = o;
}

// two sources (per-dir), contiguous per-dir dst
__global__ __launch_bounds__(256)
void cast2_kernel(const float* __restrict__ s0, const float* __restrict__ s1,
                  bf16* __restrict__ out, int n4)
{
    int i = blockIdx.x * 256 + threadIdx.x;
    if (i >= n4) return;
    int dir = blockIdx.y;
    const float* s = dir ? s1 : s0;
    float4 v = ((const float4*)s)[i];
    ushort4 o; o.x = f2bf(v.x); o.y = f2bf(v.y); o.z = f2bf(v.z); o.w = f2bf(v.w);
    ((ushort4*)(out + (size_t)dir * n4 * 4))[i] = o;
}

// x -> bf16, dir0 as-is, dir1 row-flipped
__global__ __launch_bounds__(256)
void castx_kernel(const float* __restrict__ in, bf16* __restrict__ out)
{
    int i = blockIdx.x * 256 + threadIdx.x;        // over MM*DM/4
    int dir = blockIdx.y;
    int k4 = i & (DM / 4 - 1); int m = i / (DM / 4);
    int b = m / L_, l = m % L_;
    int src = dir ? (b * L_ + (L_ - 1 - l)) : m;
    float4 v = ((const float4*)(in + (size_t)src * DM))[k4];
    ushort4 o; o.x = f2bf(v.x); o.y = f2bf(v.y); o.z = f2bf(v.z); o.w = f2bf(v.w);
    ((ushort4*)(out + (size_t)dir * MM * DM + (size_t)m * DM))[k4] = o;
}

// gated cast: actbf = bf16((ys + xc*D) * silu(z)), both dirs
__global__ __launch_bounds__(256)
void gate_cast_b(const float* __restrict__ ys, const float* __restrict__ xc,
                 const float* __restrict__ xz,
                 const float* __restrict__ D0, const float* __restrict__ D1,
                 bf16* __restrict__ out)
{
    int i = blockIdx.x * 256 + threadIdx.x;        // over 2*MM*DI/4
    int dir = i >> 20;                              // MM*DI/4 = 2^20
    int j = i & ((1 << 20) - 1);
    int d4 = j & (DI / 4 - 1); int m = j >> 9;
    const float* Dp = dir ? D1 : D0;
    float4 y = ((const float4*)(ys + (size_t)dir * MM * DI))[j];
    float4 x = ((const float4*)(xc + (size_t)dir * MM * DI))[j];
    float4 z = *(const float4*)(xz + (size_t)dir * MM * 2 * DI + (size_t)m * (2 * DI) + DI + 4 * d4);
    float4 D = ((const float4*)Dp)[d4];
    float v0 = (y.x + x.x * D.x) * (z.x / (1.f + __expf(-z.x)));
    float v1 = (y.y + x.y * D.y) * (z.y / (1.f + __expf(-z.y)));
    float v2 = (y.z + x.z * D.z) * (z.z / (1.f + __expf(-z.z)));
    float v3 = (y.w + x.w * D.w) * (z.w / (1.f + __expf(-z.w)));
    ushort4 o; o.x = f2bf(v0); o.y = f2bf(v1); o.z = f2bf(v2); o.w = f2bf(v3);
    ((ushort4*)out)[i] = o;
}

// ============ conv + silu, both dirs, writes fp32 xc AND bf16 xc ============
__global__ __launch_bounds__(256)
void conv_silu_b(const float* __restrict__ xz,
                 const float* __restrict__ cw0, const float* __restrict__ cw1,
                 const float* __restrict__ cb0, const float* __restrict__ cb1,
                 float* __restrict__ xc, bf16* __restrict__ xcbf)
{
    int idx = blockIdx.x * 256 + threadIdx.x;      // over 2*MM*DI
    int dir = idx >> 22;                            // MM*DI = 2^22
    int r = idx & ((1 << 22) - 1);
    int d = r & (DI - 1); int m = r >> 11; int l = m & (L_ - 1); int b = m >> 10;
    const float* cw = dir ? cw1 : cw0;
    const float* cb = dir ? cb1 : cb0;
    const float* xzb = xz + (size_t)dir * MM * 2 * DI;
    float acc = cb[d];
    #pragma unroll
    for (int k = 0; k < DC; k++) {
        int ls = l + k - (DC - 1);
        if (ls >= 0)
            acc += xzb[(size_t)(b * L_ + ls) * (2 * DI) + d] * cw[d * DC + k];
    }
    float v = acc / (1.f + __expf(-acc));
    xc[idx] = v;
    xcbf[idx] = __float2bfloat16(v);
}

// ========== chunk-parallel scan, d-on-lanes, both dirs ==========
// wv (global) = bd*NC + c ; bd = dir*64 + b*32 + dblk ; lane = d offset.
// P/H index = wv*1024 + n*64 + lane.
__global__ __launch_bounds__(256)
void scan_phaseA_b(const float* __restrict__ dbl, const float* __restrict__ xc,
                   const float* __restrict__ dts,
                   const float* __restrict__ a0, const float* __restrict__ a1,
                   float* __restrict__ Pbuf, float* __restrict__ Hbuf)
{
    int t = blockIdx.x * 256 + threadIdx.x;
    int lane = t & 63, wv = t >> 6;
    int c = wv & (NC - 1);
    int bd = wv >> 5;                  // dir*64 + b*32 + dblk
    int dblk = bd & 31, b = (bd >> 5) & 1, dir = bd >> 6;
    int d = dblk * 64 + lane;
    const float* A_log = dir ? a1 : a0;

    float Aval[16];
    {
        const float4* pa = (const float4*)(A_log + d * DS);
        #pragma unroll
        for (int q = 0; q < 4; q++) {
            float4 v = pa[q];
            Aval[4*q+0] = -__expf(v.x); Aval[4*q+1] = -__expf(v.y);
            Aval[4*q+2] = -__expf(v.z); Aval[4*q+3] = -__expf(v.w);
        }
    }
    float P[16], H[16];
    #pragma unroll
    for (int n = 0; n < 16; n++) { P[n] = 1.f; H[n] = 0.f; }

    int l0 = c * CL;
    const float* pdt = dts + (size_t)dir * MM * DI + (size_t)(b * L_ + l0) * DI + d;
    const float* pxc = xc  + (size_t)dir * MM * DI + (size_t)(b * L_ + l0) * DI + d;
    const float* pB  = dbl + (size_t)dir * MM * GG + (size_t)(b * L_ + l0) * GG + RK;

    for (int i = 0; i < CL; i++) {
        float dt = *pdt, x = *pxc;
        float dtx = dt * x;
        float Bn[16];
        #pragma unroll
        for (int q = 0; q < 4; q++) {
            float4 v = ((const float4*)pB)[q];
            Bn[4*q+0] = v.x; Bn[4*q+1] = v.y; Bn[4*q+2] = v.z; Bn[4*q+3] = v.w;
        }
        #pragma unroll
        for (int n = 0; n < 16; n++) {
            float dA = __expf(dt * Aval[n]);
            P[n] *= dA;
            H[n] = dA * H[n] + dtx * Bn[n];
        }
        pdt += DI; pxc += DI; pB += GG;
    }
    size_t obase = (size_t)wv * 1024 + lane;
    #pragma unroll
    for (int n = 0; n < 16; n++) { Pbuf[obase + n * 64] = P[n]; Hbuf[obase + n * 64] = H[n]; }
}

__global__ __launch_bounds__(256)
void scan_phaseB_b(const float* __restrict__ Pbuf, float* __restrict__ Hbuf)
{
    int t = blockIdx.x * 256 + threadIdx.x;   // 2*B_*32*16*64 = 131072 threads
    int lane = t & 63; int n = (t >> 6) & 15; int bd = t >> 10;   // bd in [0,128)
    size_t base = (size_t)bd * NC * 1024 + n * 64 + lane;
    float run = 0.f;
    for (int c = 0; c < NC; c++) {
        size_t idx = base + (size_t)c * 1024;
        float P  = Pbuf[idx];
        float Hl = Hbuf[idx];
        Hbuf[idx] = run;
        run = Hl + P * run;
    }
}

__global__ __launch_bounds__(256)
void scan_phaseC_b(const float* __restrict__ dbl, const float* __restrict__ xc,
                   float* __restrict__ dtys,
                   const float* __restrict__ a0, const float* __restrict__ a1,
                   const float* __restrict__ Hbuf)
{
    int t = blockIdx.x * 256 + threadIdx.x;
    int lane = t & 63, wv = t >> 6;
    int c = wv & (NC - 1);
    int bd = wv >> 5;
    int dblk = bd & 31, b = (bd >> 5) & 1, dir = bd >> 6;
    int d = dblk * 64 + lane;
    const float* A_log = dir ? a1 : a0;

    float Aval[16];
    {
        const float4* pa = (const float4*)(A_log + d * DS);
        #pragma unroll
        for (int q = 0; q < 4; q++) {
            float4 v = pa[q];
            Aval[4*q+0] = -__expf(v.x); Aval[4*q+1] = -__expf(v.y);
            Aval[4*q+2] = -__expf(v.z); Aval[4*q+3] = -__expf(v.w);
        }
    }
    float h[16];
    size_t hbase = (size_t)wv * 1024 + lane;
    #pragma unroll
    for (int n = 0; n < 16; n++) h[n] = Hbuf[hbase + n * 64];

    int l0 = c * CL;
    float*       pw  = dtys + (size_t)dir * MM * DI + (size_t)(b * L_ + l0) * DI + d;
    const float* pxc = xc   + (size_t)dir * MM * DI + (size_t)(b * L_ + l0) * DI + d;
    const float* pB  = dbl  + (size_t)dir * MM * GG + (size_t)(b * L_ + l0) * GG + RK;

    for (int i = 0; i < CL; i++) {
        float dt = *pw, x = *pxc;
        float dtx = dt * x;
        float Bn[16], Cn[16];
        #pragma unroll
        for (int q = 0; q < 4; q++) {
            float4 v = ((const float4*)pB)[q];
            Bn[4*q+0] = v.x; Bn[4*q+1] = v.y; Bn[4*q+2] = v.z; Bn[4*q+3] = v.w;
            float4 w = ((const float4*)pB)[q + 4];
            Cn[4*q+0] = w.x; Cn[4*q+1] = w.y; Cn[4*q+2] = w.z; Cn[4*q+3] = w.w;
        }
        float y = 0.f;
        #pragma unroll
        for (int n = 0; n < 16; n++) {
            float dA = __expf(dt * Aval[n]);
            h[n] = dA * h[n] + dtx * Bn[n];
            y += h[n] * Cn[n];
        }
        *pw = y;
        pw += DI; pxc += DI; pB += GG;
    }
}

// =============== LN over yo0 + yo1 ===============
__global__ __launch_bounds__(256)
void ln2_kernel(const float* __restrict__ yo, const float* __restrict__ gamma,
                const float* __restrict__ beta, float* __restrict__ out)
{
    int row = blockIdx.x;
    const float* r0 = yo + (size_t)row * DM;
    const float* r1 = yo + (size_t)MM * DM + (size_t)row * DM;
    float s = 0.f, s2 = 0.f;
    for (int i = threadIdx.x; i < DM; i += 256) {
        float v = r0[i] + r1[i]; s += v; s2 += v * v;
    }
    #pragma unroll
    for (int o = 32; o > 0; o >>= 1) { s += __shfl_down(s, o); s2 += __shfl_down(s2, o); }
    __shared__ float sw[4], sw2[4];
    int wid = threadIdx.x >> 6, ln = threadIdx.x & 63;
    if (ln == 0) { sw[wid] = s; sw2[wid] = s2; }
    __syncthreads();
    if (threadIdx.x == 0) {
        float a = 0.f, b2 = 0.f;
        for (int i = 0; i < 4; i++) { a += sw[i]; b2 += sw2[i]; }
        sw[0] = a; sw2[0] = b2;
    }
    __syncthreads();
    float mean = sw[0] / DM;
    float var  = sw2[0] / DM - mean * mean;
    float rstd = rsqrtf(var + LN_EPS);
    for (int i = threadIdx.x; i < DM; i += 256) {
        float v = (r0[i] + r1[i] - mean) * rstd;
        out[(size_t)row * DM + i] = gamma[i] * v + beta[i];
    }
}

// ================= fp32 fallback path (only if ws too small) =================
template<int EPI>
__global__ __launch_bounds__(256)
void gemm_bt(const float* __restrict__ A, int lda,
             const float* __restrict__ W, int ldw,
             float* __restrict__ C, int ldc,
             int M, int N, int K, int flipA, int flipC,
             const float* __restrict__ bias)
{
    __shared__ float As[16][65];
    __shared__ float Ws[16][65];
    const int m0 = blockIdx.y * 64;
    const int n0 = blockIdx.x * 64;
    const int tx = threadIdx.x, ty = threadIdx.y;
    const int tid = ty * 16 + tx;
    float acc[4][4] = {};

    for (int k0 = 0; k0 < K; k0 += 16) {
        for (int e = tid; e < 1024; e += 256) {
            int mm = e >> 4, kk = e & 15;
            int gm = m0 + mm, gk = k0 + kk;
            float va = 0.f;
            if (gm < M && gk < K) {
                int pr = gm;
                if (flipA) { int b = gm / L_; int l = gm % L_; pr = b * L_ + (L_ - 1 - l); }
                va = A[(size_t)pr * lda + gk];
            }
            As[kk][mm] = va;
            int gn = n0 + mm;
            float vw = 0.f;
            if (gn < N && gk < K) vw = W[(size_t)gn * ldw + gk];
            Ws[kk][mm] = vw;
        }
        __syncthreads();
        #pragma unroll
        for (int k = 0; k < 16; k++) {
            float a[4], w[4];
            #pragma unroll
            for (int i = 0; i < 4; i++) a[i] = As[k][ty * 4 + i];
            #pragma unroll
            for (int j = 0; j < 4; j++) w[j] = Ws[k][tx * 4 + j];
            #pragma unroll
            for (int i = 0; i < 4; i++)
                #pragma unroll
                for (int j = 0; j < 4; j++) acc[i][j] += a[i] * w[j];
        }
        __syncthreads();
    }

    #pragma unroll
    for (int i = 0; i < 4; i++) {
        int m = m0 + ty * 4 + i;
        if (m >= M) continue;
        int mo = m;
        if (flipC) { int b = m / L_; int l = m % L_; mo = b * L_ + (L_ - 1 - l); }
        #pragma unroll
        for (int j = 0; j < 4; j++) {
            int n = n0 + tx * 4 + j;
            if (n >= N) continue;
            float v = acc[i][j];
            if (EPI == 1) { v += bias[n]; v = (v > 20.f) ? v : log1pf(expf(v)); }
            float* p = &C[(size_t)mo * ldc + n];
            if (EPI == 2) v += *p;
            *p = v;
        }
    }
}

__global__ __launch_bounds__(256)
void conv_silu_f(const float* __restrict__ xz, const float* __restrict__ conv_w,
                 const float* __restrict__ conv_b, float* __restrict__ xc)
{
    int idx = blockIdx.x * 256 + threadIdx.x;
    int d = idx % DI; int bl = idx / DI; int l = bl % L_; int b = bl / L_;
    float acc = conv_b[d];
    #pragma unroll
    for (int k = 0; k < DC; k++) {
        int ls = l + k - (DC - 1);
        if (ls >= 0)
            acc += xz[(size_t)(b * L_ + ls) * (2 * DI) + d] * conv_w[d * DC + k];
    }
    xc[idx] = acc / (1.f + __expf(-acc));
}

__global__ __launch_bounds__(256)
void scan_kernel(const float* __restrict__ dbl, const float* __restrict__ xc,
                 float* __restrict__ dtys, const float* __restrict__ xz,
                 const float* __restrict__ A_log, const float* __restrict__ Dp)
{
    int t = blockIdx.x * 256 + threadIdx.x;
    int lane = t & 63; int w = t >> 6;
    int n = lane & 15; int dsub = lane >> 4;
    int b = w / (DI / 4); int dgrp = w % (DI / 4);
    int d = dgrp * 4 + dsub;

    float Aval = -__expf(A_log[d * DS + n]);
    float Dval = Dp[d];
    float h = 0.f;
    const float* dblb = dbl + (size_t)(b * L_) * GG;

    for (int l = 0; l < L_; l++) {
        size_t ro = (size_t)(b * L_ + l);
        float dt = dtys[ro * DI + d];
        float x  = xc[ro * DI + d];
        float Bn = dblb[l * GG + RK + n];
        float Cn = dblb[l * GG + RK + DS + n];
        float dA = __expf(dt * Aval);
        h = dA * h + dt * x * Bn;
        float c = h * Cn;
        c += __shfl_xor(c, 8, 16);
        c += __shfl_xor(c, 4, 16);
        c += __shfl_xor(c, 2, 16);
        c += __shfl_xor(c, 1, 16);
        if (n == 0) {
            float z = xz[ro * (2 * DI) + DI + d];
            float sz = z / (1.f + __expf(-z));
            dtys[ro * DI + d] = (c + x * Dval) * sz;
        }
    }
}

__global__ __launch_bounds__(256)
void ln_kernel(const float* __restrict__ yo, const float* __restrict__ gamma,
               const float* __restrict__ beta, float* __restrict__ out)
{
    int row = blockIdx.x;
    const float* r = yo + (size_t)row * DM;
    float s = 0.f, s2 = 0.f;
    for (int i = threadIdx.x; i < DM; i += 256) { float v = r[i]; s += v; s2 += v * v; }
    #pragma unroll
    for (int o = 32; o > 0; o >>= 1) { s += __shfl_down(s, o); s2 += __shfl_down(s2, o); }
    __shared__ float sw[4], sw2[4];
    int wid = threadIdx.x >> 6, ln = threadIdx.x & 63;
    if (ln == 0) { sw[wid] = s; sw2[wid] = s2; }
    __syncthreads();
    if (threadIdx.x == 0) {
        float a = 0.f, b2 = 0.f;
        for (int i = 0; i < 4; i++) { a += sw[i]; b2 += sw2[i]; }
        sw[0] = a; sw2[0] = b2;
    }
    __syncthreads();
    float mean = sw[0] / DM;
    float var  = sw2[0] / DM - mean * mean;
    float rstd = rsqrtf(var + LN_EPS);
    for (int i = threadIdx.x; i < DM; i += 256) {
        float v = (r[i] - mean) * rstd;
        out[(size_t)row * DM + i] = gamma[i] * v + beta[i];
    }
}

extern "C" void kernel_launch(void* const* d_in, const int* in_sizes, int n_in,
                              void* d_out, int out_size, void* d_ws, size_t ws_size,
                              hipStream_t stream)
{
    const float* x = (const float*)d_in[0];
    const float* W[2][9];
    for (int dir = 0; dir < 2; dir++)
        for (int k = 0; k < 9; k++)
            W[dir][k] = (const float*)d_in[1 + dir * 9 + k];
    // k: 0 in_proj, 1 conv_w, 2 conv_b, 3 x_proj, 4 dt_proj_w, 5 dt_proj_b,
    //    6 A_log, 7 D, 8 out_proj
    const float* gamma = (const float*)d_in[19];
    const float* beta  = (const float*)d_in[20];

    float* ws  = (float*)d_ws;
    float* xz  = ws;                                    // 2 * MM*2*DI = 16,777,216 f
    float* xc  = xz  + (size_t)2 * MM * 2 * DI;         // 2 * MM*DI   =  8,388,608 f
    float* dbl = xc  + (size_t)2 * MM * DI;             // 2 * MM*GG   =    393,216 f
    float* dt  = dbl + (size_t)2 * MM * GG;             //              8,388,608 f
    float* yo  = dt  + (size_t)2 * MM * DI;             // 2 * MM*DM   =  4,194,304 f
    float* Pb  = yo  + (size_t)2 * MM * DM;             //              4,194,304 f
    float* Hb  = Pb  + (size_t)2 * MM * DI * 1;         // (2*B*DI*NC*DS = 4,194,304)
    float* endf = Hb + (size_t)2 * MM * DI * 1;
    bf16* wbf   = (bf16*)endf;                          // 8,388,608 el
    bf16* actbf = wbf   + (size_t)8 * 1024 * 1024;      // 8,388,608 el
    bf16* dblbf = actbf + (size_t)8 * 1024 * 1024;      //   393,216 el
    const size_t need = (size_t)(endf - ws) * 4
                      + ((size_t)8 * 1024 * 1024 * 2 + 393216) * 2;

    if (ws_size >= need) {
        // ---- weight casts (both dirs each) ----
        cast2_kernel<<<dim3((2 * DI * DM / 4) / 256, 2), 256, 0, stream>>>(
            W[0][0], W[1][0], wbf, 2 * DI * DM / 4);                      // in_proj
        castx_kernel<<<dim3((MM * DM / 4) / 256, 2), 256, 0, stream>>>(x, actbf);

        // ---- GEMM1 both: xz = x(flip per dir) @ in_proj^T ----
        gemm_mfma_b<128, 128, 0><<<dim3(2 * DI / 128, MM / 128, 2), 256, 0, stream>>>(
            actbf, DM, (size_t)MM * DM, wbf, DM, (size_t)2 * DI * DM,
            xz, 2 * DI, (size_t)MM * 2 * DI, DM, 0, nullptr, nullptr);

        // ---- conv + silu (both dirs), fused bf16 cast of xc ----
        conv_silu_b<<<(2 * MM * DI) / 256, 256, 0, stream>>>(
            xz, W[0][1], W[1][1], W[0][2], W[1][2], xc, actbf);

        // ---- GEMM2 both (split-K, atomics) ----
        cast2_kernel<<<dim3((GG * DI / 4 + 255) / 256, 2), 256, 0, stream>>>(
            W[0][3], W[1][3], wbf, GG * DI / 4);                          // x_proj
        hipMemsetAsync(dbl, 0, (size_t)2 * MM * GG * sizeof(float), stream);
        gemm2_mfma_b<8><<<dim3(1, MM / 128, 16), 256, 0, stream>>>(actbf, wbf, dbl, DI);

        // ---- GEMM3 both: dt = softplus(dbl[:,:64] @ dt_proj^T + b) ----
        cast_kernel<<<(2 * MM * GG / 4) / 256, 256, 0, stream>>>(dbl, dblbf, 2 * MM * GG / 4);
        cast2_kernel<<<dim3((DI * RK / 4 + 255) / 256, 2), 256, 0, stream>>>(
            W[0][4], W[1][4], wbf, DI * RK / 4);                          // dt_proj_w
        gemm_mfma_b<128, 128, 1><<<dim3(DI / 128, MM / 128, 2), 256, 0, stream>>>(
            dblbf, GG, (size_t)MM * GG, wbf, RK, (size_t)DI * RK,
            dt, DI, (size_t)MM * DI, RK, 0, W[0][5], W[1][5]);

        // ---- scan (both dirs) ----
        scan_phaseA_b<<<1024, 256, 0, stream>>>(dbl, xc, dt, W[0][6], W[1][6], Pb, Hb);
        scan_phaseB_b<<<512, 256, 0, stream>>>(Pb, Hb);
        scan_phaseC_b<<<1024, 256, 0, stream>>>(dbl, xc, dt, W[0][6], W[1][6], Hb);

        // ---- gate + cast, then GEMM4 both (dir1 stores flipped into yo1) ----
        gate_cast_b<<<(2 * MM * DI / 4) / 256, 256, 0, stream>>>(
            dt, xc, xz, W[0][7], W[1][7], actbf);
        cast2_kernel<<<dim3((DM * DI / 4) / 256, 2), 256, 0, stream>>>(
            W[0][8], W[1][8], wbf, DM * DI / 4);                          // out_proj
        gemm_mfma_b<128, 64, 0><<<dim3(DM / 64, MM / 128, 2), 256, 0, stream>>>(
            actbf, DI, (size_t)MM * DI, wbf, DI, (size_t)DM * DI,
            yo, DM, (size_t)MM * DM, DI, 1, nullptr, nullptr);

        // ---- LN over yo0 + yo1 ----
        ln2_kernel<<<MM, 256, 0, stream>>>(yo, gamma, beta, (float*)d_out);
    } else {
        // ---------- compact fp32 fallback ----------
        dim3 blk(16, 16);
        for (int dir = 0; dir < 2; dir++) {
            gemm_bt<0><<<dim3((2 * DI) / 64, MM / 64), blk, 0, stream>>>(
                x, DM, W[dir][0], DM, xz, 2 * DI, MM, 2 * DI, DM, dir, 0, nullptr);
            conv_silu_f<<<(MM * DI) / 256, 256, 0, stream>>>(xz, W[dir][1], W[dir][2], xc);
            gemm_bt<0><<<dim3((GG + 63) / 64, MM / 64), blk, 0, stream>>>(
                xc, DI, W[dir][3], DI, dbl, GG, MM, GG, DI, 0, 0, nullptr);
            gemm_bt<1><<<dim3(DI / 64, MM / 64), blk, 0, stream>>>(
                dbl, GG, W[dir][4], RK, dt, DI, MM, DI, RK, 0, 0, W[dir][5]);
            scan_kernel<<<256, 256, 0, stream>>>(dbl, xc, dt, xz, W[dir][6], W[dir][7]);
            if (dir == 0)
                gemm_bt<0><<<dim3(DM / 64, MM / 64), blk, 0, stream>>>(
                    dt, DI, W[dir][8], DI, yo, DM, MM, DM, DI, 0, 0, nullptr);
            else
                gemm_bt<2><<<dim3(DM / 64, MM / 64), blk, 0, stream>>>(
                    dt, DI, W[dir][8], DI, yo, DM, MM, DM, DI, 0, 1, nullptr);
        }
        ln_kernel<<<MM, 256, 0, stream>>>(yo, gamma, beta, (float*)d_out);
    }
}